// Round 5
// baseline (274457.397 us; speedup 1.0000x reference)
//
#include <hip/hip_runtime.h>
#include <cstdint>
#include <cmath>

// ---------------------------------------------------------------------------
// DDSP decoder on MI355X — inputs/outputs float32 (per reference dtypes).
//   1) precompute: gi_t = f0_t*U + loud_t*V + W  (input GEMM is rank-2+const)
//   2) persistent GRU: 128 blocks x 256 thr; Wh slice (8 cols x 3 gates, f32)
//      staged in LDS (96 KB) — compiler-proof residency (r3/r4: VGPR arrays
//      were spilled/sunk -> per-step L2 refetch, 8.2us/step, VGPR stuck at 124).
//      Parallel flag-array device barrier (r3/r4 central atomicAdd serialized
//      64 RMWs/step). f32 double-buffered h state; h history bf16 [T,H].
//   3) 3x (64x64-tile GEMM bf16-in/f32-acc/bf16-out + bias) + LN+ReLU.
//   4) heads: per-t block; amp/harm/noise projections, exp_sigmoid, normalize.
// ---------------------------------------------------------------------------

#define T_STEPS 32768
#define H_DIM   1024
#define H3      3072
#define NHARM   100
#define NNOISE  65
#define GRU_NB  128
#define GRU_CPB 8      // columns (h outputs) per block

typedef unsigned short u16;

__device__ __forceinline__ float b2f(u16 u) {
  union { unsigned u; float f; } x; x.u = ((unsigned)u) << 16; return x.f;
}
__device__ __forceinline__ u16 f2b(float f) {
  unsigned v = __float_as_uint(f);
  unsigned r = (v + 0x7FFFu + ((v >> 16) & 1u)) >> 16;  // RNE
  return (u16)r;
}
__device__ __forceinline__ float sigm(float x) { return 1.0f / (1.0f + expf(-x)); }
__device__ __forceinline__ float exp_sig(float x) {
  // 2.0 * sigmoid(x)^ln(10) + 1e-7
  float s = sigm(x);
  return 2.0f * expf(2.302585093f * logf(s)) + 1e-7f;
}

// ---------------------------------------------------------------------------
// 1) U[j] = sum_h Win[0,h]*Wi[h,j]; V[j] = sum_h Win[1,h]*Wi[h,j];
//    W[j] = sum_h bin[h]*Wi[h,j].  Blocks 12..15 init h-buffer + flags.
// ---------------------------------------------------------------------------
__global__ __launch_bounds__(256) void ddsp_precompute(
    const float* __restrict__ Win, const float* __restrict__ bin,
    const float* __restrict__ Wi, const float* __restrict__ h0,
    float* __restrict__ U, float* __restrict__ V, float* __restrict__ Wc,
    float* __restrict__ hbuf, unsigned* __restrict__ flags)
{
  const int gid = blockIdx.x * 256 + threadIdx.x;
  if (blockIdx.x < 12) {
    const int j = gid;  // 0..3071
    float su = 0.f, sv = 0.f, sw = 0.f;
    for (int h = 0; h < H_DIM; ++h) {
      const float wv = Wi[h * H3 + j];        // lanes j consecutive -> coalesced
      su = fmaf(Win[h], wv, su);
      sv = fmaf(Win[H_DIM + h], wv, sv);
      sw = fmaf(bin[h], wv, sw);
    }
    U[j] = su; V[j] = sv; Wc[j] = sw;
  } else {
    const int idx = gid - 12 * 256;           // 0..1023
    hbuf[idx] = h0[idx];
    if (idx < GRU_NB) flags[idx] = 0u;        // ws is poisoned 0xAA -> must init
  }
}

// ---------------------------------------------------------------------------
// 2) persistent GRU.  128 blocks x 256 thr.  thread = (jl = tid>>5 col 0..7,
//    i = tid&31 k-chunk).  Wh slice [3][8][1024] f32 staged in LDS once (the
//    compiler cannot sink explicit LDS ops into the t-loop).  Per step:
//    24 ds_read_b128 (bank-rotated, uniform) + 96 FMA per thread, 32-lane
//    butterfly reduce, gate math on i==0, flag-array device barrier.
//    Cross-block h exchange uses agent-scope atomics (XCD L2 non-coherence).
// ---------------------------------------------------------------------------
__global__ __launch_bounds__(256, 1) void ddsp_gru(
    const float* __restrict__ f0, const float* __restrict__ loud,
    const float* __restrict__ Wh, const float* __restrict__ bh,
    const float* __restrict__ U, const float* __restrict__ V,
    const float* __restrict__ Wc,
    float* __restrict__ hbuf, unsigned* __restrict__ flags,
    u16* __restrict__ hall)
{
  __shared__ float wlds[3 * GRU_CPB * H_DIM];  // 96 KB: [g][c][k]
  __shared__ float lds_h[H_DIM];               // 4 KB
  const int tid = threadIdx.x;
  const int i  = tid & 31;
  const int jl = tid >> 5;
  const int jg = blockIdx.x * GRU_CPB + jl;

  // One-time LDS weight stage: wlds[g][c][k] = Wh[k][g*1024 + block*8 + c].
  // Uncoalesced global reads (stride 12KB) but a one-time ~100KB/block cost.
  for (int g = 0; g < 3; ++g) {
    for (int c = 0; c < GRU_CPB; ++c) {
      const int col = g * H_DIM + blockIdx.x * GRU_CPB + c;
#pragma unroll
      for (int e = 0; e < 4; ++e) {
        const int k = tid * 4 + e;
        wlds[(g * GRU_CPB + c) * H_DIM + k] = Wh[(size_t)k * H3 + col];
      }
    }
  }

  float ur = 0.f, uz = 0.f, un = 0.f, vr = 0.f, vz = 0.f, vn = 0.f;
  float wr = 0.f, wz = 0.f, wn = 0.f, bhr = 0.f, bhz = 0.f, bhn = 0.f;
  if (i == 0) {
    ur = U[jg]; uz = U[jg + 1024]; un = U[jg + 2048];
    vr = V[jg]; vz = V[jg + 1024]; vn = V[jg + 2048];
    wr = Wc[jg]; wz = Wc[jg + 1024]; wn = Wc[jg + 2048];
    bhr = bh[jg]; bhz = bh[jg + 1024]; bhn = bh[jg + 2048];
  }
  __syncthreads();

  const float* wl0 = wlds + (0 * GRU_CPB + jl) * H_DIM;
  const float* wl1 = wlds + (1 * GRU_CPB + jl) * H_DIM;
  const float* wl2 = wlds + (2 * GRU_CPB + jl) * H_DIM;

  for (int t = 0; t < T_STEPS; ++t) {
    const float* hcur = hbuf + (t & 1) * H_DIM;
    float* hnxt = hbuf + ((t + 1) & 1) * H_DIM;

    // stage h_t into LDS (agent-scope loads -> coherence point, no stale L1)
#pragma unroll
    for (int e = 0; e < 4; ++e) {
      lds_h[tid * 4 + e] = __hip_atomic_load(hcur + tid * 4 + e,
                                             __ATOMIC_RELAXED, __HIP_MEMORY_SCOPE_AGENT);
    }
    __syncthreads();

    float a0 = 0.f, a1 = 0.f, a2 = 0.f;
    const int kbase = i << 5;  // i*32
#pragma unroll
    for (int it = 0; it < 8; ++it) {
      const int kk = kbase + (((it + i) & 7) << 2);  // rotation: uniform banks
      const float4 h4 = *(const float4*)(lds_h + kk);
      const float4 wa = *(const float4*)(wl0 + kk);
      const float4 wb = *(const float4*)(wl1 + kk);
      const float4 wc4 = *(const float4*)(wl2 + kk);
      a0 = fmaf(wa.x, h4.x, a0); a0 = fmaf(wa.y, h4.y, a0);
      a0 = fmaf(wa.z, h4.z, a0); a0 = fmaf(wa.w, h4.w, a0);
      a1 = fmaf(wb.x, h4.x, a1); a1 = fmaf(wb.y, h4.y, a1);
      a1 = fmaf(wb.z, h4.z, a1); a1 = fmaf(wb.w, h4.w, a1);
      a2 = fmaf(wc4.x, h4.x, a2); a2 = fmaf(wc4.y, h4.y, a2);
      a2 = fmaf(wc4.z, h4.z, a2); a2 = fmaf(wc4.w, h4.w, a2);
    }
    // butterfly reduce over the 32-lane group (masks stay within wave half)
#pragma unroll
    for (int m = 1; m < 32; m <<= 1) {
      a0 += __shfl_xor(a0, m);
      a1 += __shfl_xor(a1, m);
      a2 += __shfl_xor(a2, m);
    }
    if (i == 0) {
      const float fv = f0[t];
      const float lv = loud[t];
      const float gir = fmaf(fv, ur, fmaf(lv, vr, wr));
      const float giz = fmaf(fv, uz, fmaf(lv, vz, wz));
      const float gin = fmaf(fv, un, fmaf(lv, vn, wn));
      const float r = sigm(gir + a0 + bhr);
      const float z = sigm(giz + a1 + bhz);
      const float n = tanhf(fmaf(r, a2 + bhn, gin));  // b_h[n] inside r*( )
      const float hp = lds_h[jg];
      const float hn = (1.0f - z) * n + z * hp;
      __hip_atomic_store(hnxt + jg, hn, __ATOMIC_RELAXED, __HIP_MEMORY_SCOPE_AGENT);
      hall[(size_t)t * H_DIM + jg] = f2b(hn);
    }
    __syncthreads();  // drains each thread's stores (vmcnt(0) before s_barrier)

    // parallel flag barrier: arrive (release) then wave 0 polls all flags
    if (tid == 0) {
      __hip_atomic_store(&flags[blockIdx.x], (unsigned)(t + 1),
                         __ATOMIC_RELEASE, __HIP_MEMORY_SCOPE_AGENT);
    }
    if (tid < 64) {
      const unsigned tgt = (unsigned)(t + 1);
      bool ok;
      do {
        const unsigned fa = __hip_atomic_load(&flags[tid * 2],
                                              __ATOMIC_RELAXED, __HIP_MEMORY_SCOPE_AGENT);
        const unsigned fb = __hip_atomic_load(&flags[tid * 2 + 1],
                                              __ATOMIC_RELAXED, __HIP_MEMORY_SCOPE_AGENT);
        ok = (fa >= tgt) && (fb >= tgt);
      } while (!__all(ok));
      __threadfence();  // acquire before next step's h loads
    }
    __syncthreads();
  }
}

// ---------------------------------------------------------------------------
// 3a) Y[T,1024](bf16) = X[T,1024](bf16) @ W[1024,1024](f32) + bias(f32)
//     64x64 tile, 256 thr, 4x4 micro-tile, K-step 16, f32 accumulate.
// ---------------------------------------------------------------------------
__global__ __launch_bounds__(256) void ddsp_gemm_bias(
    const u16* __restrict__ X, const float* __restrict__ Wt,
    const float* __restrict__ bias, u16* __restrict__ Y)
{
  __shared__ float As[16][64];  // transposed A tile: As[kk][m]
  __shared__ float Bs[16][64];
  const int tid = threadIdx.x;
  const int R0 = blockIdx.x * 64;
  const int N0 = blockIdx.y * 64;
  const int tx = tid & 15, ty = tid >> 4;
  const int am = tid >> 2, ak = (tid & 3) * 4;   // A staging
  const int bk = tid >> 4, bn = (tid & 15) * 4;  // B staging
  float acc[4][4] = {};

  for (int k0 = 0; k0 < H_DIM; k0 += 16) {
    const ushort4 a4 = *(const ushort4*)(X + (size_t)(R0 + am) * H_DIM + k0 + ak);
    const float4 b4 = *(const float4*)(Wt + (size_t)(k0 + bk) * H_DIM + N0 + bn);
    As[ak + 0][am] = b2f(a4.x); As[ak + 1][am] = b2f(a4.y);
    As[ak + 2][am] = b2f(a4.z); As[ak + 3][am] = b2f(a4.w);
    *(float4*)&Bs[bk][bn] = b4;
    __syncthreads();
#pragma unroll
    for (int kk = 0; kk < 16; ++kk) {
      const float4 av = *(const float4*)&As[kk][ty * 4];
      const float4 bv = *(const float4*)&Bs[kk][tx * 4];
      const float a[4] = {av.x, av.y, av.z, av.w};
      const float b[4] = {bv.x, bv.y, bv.z, bv.w};
#pragma unroll
      for (int mi = 0; mi < 4; ++mi)
#pragma unroll
        for (int ni = 0; ni < 4; ++ni)
          acc[mi][ni] = fmaf(a[mi], b[ni], acc[mi][ni]);
    }
    __syncthreads();
  }
  const float4 bv4 = *(const float4*)(bias + N0 + tx * 4);
#pragma unroll
  for (int mi = 0; mi < 4; ++mi) {
    ushort4 st;
    st.x = f2b(acc[mi][0] + bv4.x);
    st.y = f2b(acc[mi][1] + bv4.y);
    st.z = f2b(acc[mi][2] + bv4.z);
    st.w = f2b(acc[mi][3] + bv4.w);
    *(ushort4*)(Y + (size_t)(R0 + ty * 4 + mi) * H_DIM + N0 + tx * 4) = st;
  }
}

// ---------------------------------------------------------------------------
// 3b) in-place LayerNorm + ReLU over bf16 rows of Y (block = row).
// ---------------------------------------------------------------------------
__global__ __launch_bounds__(256) void ddsp_ln_relu(
    u16* __restrict__ Y, const float* __restrict__ scale, const float* __restrict__ bias)
{
  __shared__ float wsum[4], wsq[4];
  const int row = blockIdx.x, tid = threadIdx.x;
  const ushort4 r4 = *(const ushort4*)(Y + (size_t)row * H_DIM + tid * 4);
  float x[4] = {b2f(r4.x), b2f(r4.y), b2f(r4.z), b2f(r4.w)};
  float s = x[0] + x[1] + x[2] + x[3];
  float q = x[0] * x[0] + x[1] * x[1] + x[2] * x[2] + x[3] * x[3];
#pragma unroll
  for (int off = 32; off >= 1; off >>= 1) {
    s += __shfl_down(s, off);
    q += __shfl_down(q, off);
  }
  if ((tid & 63) == 0) { wsum[tid >> 6] = s; wsq[tid >> 6] = q; }
  __syncthreads();
  const float ts = wsum[0] + wsum[1] + wsum[2] + wsum[3];
  const float tq = wsq[0] + wsq[1] + wsq[2] + wsq[3];
  const float mu = ts * (1.0f / H_DIM);
  const float var = tq * (1.0f / H_DIM) - mu * mu;
  const float rstd = rsqrtf(fmaxf(var, 0.f) + 1e-6f);
  const float4 sc = *(const float4*)(scale + tid * 4);
  const float4 bi = *(const float4*)(bias + tid * 4);
  ushort4 st;
  st.x = f2b(fmaxf((x[0] - mu) * rstd * sc.x + bi.x, 0.f));
  st.y = f2b(fmaxf((x[1] - mu) * rstd * sc.y + bi.y, 0.f));
  st.z = f2b(fmaxf((x[2] - mu) * rstd * sc.z + bi.z, 0.f));
  st.w = f2b(fmaxf((x[3] - mu) * rstd * sc.w + bi.w, 0.f));
  *(ushort4*)(Y + (size_t)row * H_DIM + tid * 4) = st;
}

// ---------------------------------------------------------------------------
// 4) heads: block = timestep. threads 0..99 harm, 100..164 noise, 165 amp.
//    Hf is bf16; weights/bias/output f32.
// ---------------------------------------------------------------------------
__global__ __launch_bounds__(256) void ddsp_heads(
    const u16* __restrict__ Hf,
    const float* __restrict__ aW, const float* __restrict__ ab,
    const float* __restrict__ hW, const float* __restrict__ hb,
    const float* __restrict__ nW, const float* __restrict__ nb,
    float* __restrict__ out)
{
  __shared__ float lh[H_DIM];
  __shared__ float se[128];
  __shared__ float sred[2];  // [0]=amp, [1]=harm sum
  const int t = blockIdx.x, tid = threadIdx.x;
  const ushort4 h4 = *(const ushort4*)(Hf + (size_t)t * H_DIM + tid * 4);
  lh[tid * 4 + 0] = b2f(h4.x); lh[tid * 4 + 1] = b2f(h4.y);
  lh[tid * 4 + 2] = b2f(h4.z); lh[tid * 4 + 3] = b2f(h4.w);
  __syncthreads();

  if (tid < NHARM) {
    float acc = 0.f;
    for (int k = 0; k < H_DIM; k += 4) {
      const float4 hv = *(const float4*)(lh + k);
      acc = fmaf(hv.x, hW[(k + 0) * NHARM + tid], acc);
      acc = fmaf(hv.y, hW[(k + 1) * NHARM + tid], acc);
      acc = fmaf(hv.z, hW[(k + 2) * NHARM + tid], acc);
      acc = fmaf(hv.w, hW[(k + 3) * NHARM + tid], acc);
    }
    se[tid] = exp_sig(acc + hb[tid]);
  } else if (tid < NHARM + NNOISE) {
    const int n = tid - NHARM;
    float acc = 0.f;
    for (int k = 0; k < H_DIM; k += 4) {
      const float4 hv = *(const float4*)(lh + k);
      acc = fmaf(hv.x, nW[(k + 0) * NNOISE + n], acc);
      acc = fmaf(hv.y, nW[(k + 1) * NNOISE + n], acc);
      acc = fmaf(hv.z, nW[(k + 2) * NNOISE + n], acc);
      acc = fmaf(hv.w, nW[(k + 3) * NNOISE + n], acc);
    }
    out[(size_t)T_STEPS * NHARM + (size_t)t * NNOISE + n] = acc + nb[n];
  } else if (tid == NHARM + NNOISE) {
    float acc = 0.f;
    for (int k = 0; k < H_DIM; k += 4) {
      const float4 hv = *(const float4*)(lh + k);
      acc = fmaf(hv.x, aW[k + 0], acc);
      acc = fmaf(hv.y, aW[k + 1], acc);
      acc = fmaf(hv.z, aW[k + 2], acc);
      acc = fmaf(hv.w, aW[k + 3], acc);
    }
    sred[0] = exp_sig(acc + ab[0]);
  }
  if (tid >= NHARM && tid < 128) se[tid] = 0.f;  // pad for reduce
  __syncthreads();
  if (tid < 64) {
    float s2 = se[tid] + se[tid + 64];
#pragma unroll
    for (int off = 32; off >= 1; off >>= 1) s2 += __shfl_down(s2, off);
    if (tid == 0) sred[1] = s2;
  }
  __syncthreads();
  if (tid < NHARM) {
    out[(size_t)t * NHARM + tid] = sred[0] * se[tid] / (sred[1] + 1e-8f);
  }
}

// ---------------------------------------------------------------------------
extern "C" void kernel_launch(void* const* d_in, const int* in_sizes, int n_in,
                              void* d_out, int out_size, void* d_ws, size_t ws_size,
                              hipStream_t stream)
{
  (void)in_sizes; (void)n_in; (void)out_size;
  const float* f0   = (const float*)d_in[0];
  const float* loud = (const float*)d_in[1];
  const float* Win  = (const float*)d_in[2];
  const float* bin  = (const float*)d_in[3];
  const float* Wi   = (const float*)d_in[4];
  const float* Wh   = (const float*)d_in[5];
  const float* bh   = (const float*)d_in[6];
  const float* h0   = (const float*)d_in[7];
  const float* mlpW = (const float*)d_in[8];
  const float* mlpb = (const float*)d_in[9];
  const float* lnS  = (const float*)d_in[10];
  const float* lnB  = (const float*)d_in[11];
  const float* aW   = (const float*)d_in[12];
  const float* ab   = (const float*)d_in[13];
  const float* hW   = (const float*)d_in[14];
  const float* hb   = (const float*)d_in[15];
  const float* nW   = (const float*)d_in[16];
  const float* nb   = (const float*)d_in[17];
  float* out = (float*)d_out;

  char* ws = (char*)d_ws;
  float*    U     = (float*)(ws);                    // 3072 f32
  float*    V     = (float*)(ws + 12288);            // 3072 f32
  float*    Wc    = (float*)(ws + 24576);            // 3072 f32
  float*    hbuf  = (float*)(ws + 36864);            // 2 x 1024 f32
  unsigned* flags = (unsigned*)(ws + 45056);         // 128 u32 barrier flags
  u16* bufA = (u16*)(ws + 45568);                               // [T,H] bf16
  u16* bufB = (u16*)(ws + 45568 + (size_t)T_STEPS * H_DIM * 2); // [T,H] bf16

  const size_t needed = 45568 + 2 * (size_t)T_STEPS * H_DIM * 2;  // ~134.3 MB
  if (ws_size < needed) {
    // Workspace too small: do nothing -> bench reports absmax == max|ref|,
    // telling us ws_size is the constraint (vs a kernel fault).
    return;
  }

  ddsp_precompute<<<16, 256, 0, stream>>>(Win, bin, Wi, h0, U, V, Wc, hbuf, flags);
  ddsp_gru<<<GRU_NB, 256, 0, stream>>>(f0, loud, Wh, bh, U, V, Wc, hbuf, flags, bufA);

  dim3 gg(T_STEPS / 64, H_DIM / 64);
  ddsp_gemm_bias<<<gg, 256, 0, stream>>>(bufA, mlpW, mlpb, bufB);
  ddsp_ln_relu<<<T_STEPS, 256, 0, stream>>>(bufB, lnS, lnB);
  ddsp_gemm_bias<<<gg, 256, 0, stream>>>(bufB, mlpW + (size_t)H_DIM * H_DIM, mlpb + H_DIM, bufA);
  ddsp_ln_relu<<<T_STEPS, 256, 0, stream>>>(bufA, lnS + H_DIM, lnB + H_DIM);
  ddsp_gemm_bias<<<gg, 256, 0, stream>>>(bufA, mlpW + 2 * (size_t)H_DIM * H_DIM, mlpb + 2 * H_DIM, bufB);
  ddsp_ln_relu<<<T_STEPS, 256, 0, stream>>>(bufB, lnS + 2 * H_DIM, lnB + 2 * H_DIM);

  ddsp_heads<<<T_STEPS, 256, 0, stream>>>(bufB, aW, ab, hW, hb, nW, nb, out);
}

// Round 6
// 204405.078 us; speedup vs baseline: 1.3427x; 1.3427x over previous
//
#include <hip/hip_runtime.h>
#include <cstdint>
#include <cmath>

// ---------------------------------------------------------------------------
// DDSP decoder on MI355X — inputs/outputs float32 (per reference dtypes).
//   1) precompute: gi_t = f0_t*U + loud_t*V + W  (input GEMM is rank-2+const)
//   2) persistent GRU: 128 blocks x 256 thr; Wh slice (8 cols x 3 gates, f32)
//      staged in LDS (96 KB). FENCE-FREE device barrier: r5 showed agent-scope
//      __threadfence / release-store lower to buffer_wbl2+buffer_inv (full L2
//      writeback/invalidate) per block per step -> FETCH/WRITE ballooned to
//      1.04/0.93 GB and 9.2us/step. All cross-block data moves via RELAXED
//      agent atomics (cache-bypass); ordering via s_waitcnt vmcnt(0) + the
//      barrier's own drain. No cache maintenance in the t-loop.
//   3) 3x (64x64-tile GEMM bf16-in/f32-acc/bf16-out + bias) + LN+ReLU.
//   4) heads: per-t block; amp/harm/noise projections, exp_sigmoid, normalize.
// ---------------------------------------------------------------------------

#define T_STEPS 32768
#define H_DIM   1024
#define H3      3072
#define NHARM   100
#define NNOISE  65
#define GRU_NB  128
#define GRU_CPB 8      // columns (h outputs) per block

typedef unsigned short u16;

__device__ __forceinline__ float b2f(u16 u) {
  union { unsigned u; float f; } x; x.u = ((unsigned)u) << 16; return x.f;
}
__device__ __forceinline__ u16 f2b(float f) {
  unsigned v = __float_as_uint(f);
  unsigned r = (v + 0x7FFFu + ((v >> 16) & 1u)) >> 16;  // RNE
  return (u16)r;
}
__device__ __forceinline__ float sigm(float x) { return 1.0f / (1.0f + expf(-x)); }
__device__ __forceinline__ float exp_sig(float x) {
  // 2.0 * sigmoid(x)^ln(10) + 1e-7
  float s = sigm(x);
  return 2.0f * expf(2.302585093f * logf(s)) + 1e-7f;
}

// ---------------------------------------------------------------------------
// 1) U[j] = sum_h Win[0,h]*Wi[h,j]; V[j] = sum_h Win[1,h]*Wi[h,j];
//    W[j] = sum_h bin[h]*Wi[h,j].  Blocks 12..15 init h-buffer + flags.
// ---------------------------------------------------------------------------
__global__ __launch_bounds__(256) void ddsp_precompute(
    const float* __restrict__ Win, const float* __restrict__ bin,
    const float* __restrict__ Wi, const float* __restrict__ h0,
    float* __restrict__ U, float* __restrict__ V, float* __restrict__ Wc,
    float* __restrict__ hbuf, unsigned* __restrict__ flags)
{
  const int gid = blockIdx.x * 256 + threadIdx.x;
  if (blockIdx.x < 12) {
    const int j = gid;  // 0..3071
    float su = 0.f, sv = 0.f, sw = 0.f;
    for (int h = 0; h < H_DIM; ++h) {
      const float wv = Wi[h * H3 + j];        // lanes j consecutive -> coalesced
      su = fmaf(Win[h], wv, su);
      sv = fmaf(Win[H_DIM + h], wv, sv);
      sw = fmaf(bin[h], wv, sw);
    }
    U[j] = su; V[j] = sv; Wc[j] = sw;
  } else {
    const int idx = gid - 12 * 256;           // 0..1023
    hbuf[idx] = h0[idx];
    if (idx < GRU_NB) flags[idx] = 0u;        // ws is poisoned 0xAA -> must init
  }
}

// ---------------------------------------------------------------------------
// 2) persistent GRU.  128 blocks x 256 thr.  thread = (jl = tid>>5 col 0..7,
//    i = tid&31 k-chunk).  Wh slice [3][8][1024] f32 staged in LDS once.
//    Per step: bypass-load h -> LDS, 24 ds_read_b128 + 96 FMA per thread,
//    32-lane butterfly reduce, gate math on i==0, fence-free flag barrier:
//      producer: relaxed bypass h-stores -> s_waitcnt vmcnt(0) (+barrier
//                drain) -> relaxed flag store
//      consumer: poll flags (relaxed bypass loads; loop exit is control-
//                dependent on the loaded value -> HW ordering) -> bypass
//                h loads next iteration.  No wbl2/inv anywhere in the loop.
// ---------------------------------------------------------------------------
__global__ __launch_bounds__(256, 1) void ddsp_gru(
    const float* __restrict__ f0, const float* __restrict__ loud,
    const float* __restrict__ Wh, const float* __restrict__ bh,
    const float* __restrict__ U, const float* __restrict__ V,
    const float* __restrict__ Wc,
    float* __restrict__ hbuf, unsigned* __restrict__ flags,
    u16* __restrict__ hall)
{
  __shared__ float wlds[3 * GRU_CPB * H_DIM];  // 96 KB: [g][c][k]
  __shared__ float lds_h[H_DIM];               // 4 KB
  const int tid = threadIdx.x;
  const int i  = tid & 31;
  const int jl = tid >> 5;
  const int jg = blockIdx.x * GRU_CPB + jl;

  // One-time LDS weight stage: wlds[g][c][k] = Wh[k][g*1024 + block*8 + c].
  for (int g = 0; g < 3; ++g) {
    for (int c = 0; c < GRU_CPB; ++c) {
      const int col = g * H_DIM + blockIdx.x * GRU_CPB + c;
#pragma unroll
      for (int e = 0; e < 4; ++e) {
        const int k = tid * 4 + e;
        wlds[(g * GRU_CPB + c) * H_DIM + k] = Wh[(size_t)k * H3 + col];
      }
    }
  }

  float ur = 0.f, uz = 0.f, un = 0.f, vr = 0.f, vz = 0.f, vn = 0.f;
  float wr = 0.f, wz = 0.f, wn = 0.f, bhr = 0.f, bhz = 0.f, bhn = 0.f;
  if (i == 0) {
    ur = U[jg]; uz = U[jg + 1024]; un = U[jg + 2048];
    vr = V[jg]; vz = V[jg + 1024]; vn = V[jg + 2048];
    wr = Wc[jg]; wz = Wc[jg + 1024]; wn = Wc[jg + 2048];
    bhr = bh[jg]; bhz = bh[jg + 1024]; bhn = bh[jg + 2048];
  }
  __syncthreads();

  const float* wl0 = wlds + (0 * GRU_CPB + jl) * H_DIM;
  const float* wl1 = wlds + (1 * GRU_CPB + jl) * H_DIM;
  const float* wl2 = wlds + (2 * GRU_CPB + jl) * H_DIM;

  for (int t = 0; t < T_STEPS; ++t) {
    const float* hcur = hbuf + (t & 1) * H_DIM;
    float* hnxt = hbuf + ((t + 1) & 1) * H_DIM;

    // stage h_t into LDS via cache-bypass loads (relaxed agent atomics)
#pragma unroll
    for (int e = 0; e < 4; ++e) {
      lds_h[tid * 4 + e] = __hip_atomic_load(hcur + tid * 4 + e,
                                             __ATOMIC_RELAXED, __HIP_MEMORY_SCOPE_AGENT);
    }
    __syncthreads();

    float a0 = 0.f, a1 = 0.f, a2 = 0.f;
    const int kbase = i << 5;  // i*32
#pragma unroll
    for (int it = 0; it < 8; ++it) {
      const int kk = kbase + (((it + i) & 7) << 2);  // per-lane rotation: 4-way max
      const float4 h4 = *(const float4*)(lds_h + kk);
      const float4 wa = *(const float4*)(wl0 + kk);
      const float4 wb = *(const float4*)(wl1 + kk);
      const float4 wc4 = *(const float4*)(wl2 + kk);
      a0 = fmaf(wa.x, h4.x, a0); a0 = fmaf(wa.y, h4.y, a0);
      a0 = fmaf(wa.z, h4.z, a0); a0 = fmaf(wa.w, h4.w, a0);
      a1 = fmaf(wb.x, h4.x, a1); a1 = fmaf(wb.y, h4.y, a1);
      a1 = fmaf(wb.z, h4.z, a1); a1 = fmaf(wb.w, h4.w, a1);
      a2 = fmaf(wc4.x, h4.x, a2); a2 = fmaf(wc4.y, h4.y, a2);
      a2 = fmaf(wc4.z, h4.z, a2); a2 = fmaf(wc4.w, h4.w, a2);
    }
    // butterfly reduce over the 32-lane group
#pragma unroll
    for (int m = 1; m < 32; m <<= 1) {
      a0 += __shfl_xor(a0, m);
      a1 += __shfl_xor(a1, m);
      a2 += __shfl_xor(a2, m);
    }
    if (i == 0) {
      const float fv = f0[t];
      const float lv = loud[t];
      const float gir = fmaf(fv, ur, fmaf(lv, vr, wr));
      const float giz = fmaf(fv, uz, fmaf(lv, vz, wz));
      const float gin = fmaf(fv, un, fmaf(lv, vn, wn));
      const float r = sigm(gir + a0 + bhr);
      const float z = sigm(giz + a1 + bhz);
      const float n = tanhf(fmaf(r, a2 + bhn, gin));  // b_h[n] inside r*( )
      const float hp = lds_h[jg];
      const float hn = (1.0f - z) * n + z * hp;
      __hip_atomic_store(hnxt + jg, hn, __ATOMIC_RELAXED, __HIP_MEMORY_SCOPE_AGENT);
      hall[(size_t)t * H_DIM + jg] = f2b(hn);
    }
    // Drain this wave's stores, then workgroup barrier (emits its own
    // vmcnt(0) per wave). After this point every h store of this block has
    // completed at the coherence point — no cache flush needed (bypass).
    asm volatile("s_waitcnt vmcnt(0)" ::: "memory");
    __syncthreads();

    // arrive: relaxed flag store (ordered after h stores by the drain above)
    if (tid == 0) {
      __hip_atomic_store(&flags[blockIdx.x], (unsigned)(t + 1),
                         __ATOMIC_RELAXED, __HIP_MEMORY_SCOPE_AGENT);
    }
    // wait: wave 0 polls all 128 flags (2 per lane). Loop exit is control-
    // dependent on the loaded values -> subsequent bypass loads are ordered.
    if (tid < 64) {
      const unsigned tgt = (unsigned)(t + 1);
      bool ok;
      do {
        const unsigned fa = __hip_atomic_load(&flags[tid * 2],
                                              __ATOMIC_RELAXED, __HIP_MEMORY_SCOPE_AGENT);
        const unsigned fb = __hip_atomic_load(&flags[tid * 2 + 1],
                                              __ATOMIC_RELAXED, __HIP_MEMORY_SCOPE_AGENT);
        ok = (fa >= tgt) && (fb >= tgt);
      } while (!__all(ok));
    }
    asm volatile("" ::: "memory");  // compiler ordering pin (no HW op)
    __syncthreads();
  }
}

// ---------------------------------------------------------------------------
// 3a) Y[T,1024](bf16) = X[T,1024](bf16) @ W[1024,1024](f32) + bias(f32)
//     64x64 tile, 256 thr, 4x4 micro-tile, K-step 16, f32 accumulate.
// ---------------------------------------------------------------------------
__global__ __launch_bounds__(256) void ddsp_gemm_bias(
    const u16* __restrict__ X, const float* __restrict__ Wt,
    const float* __restrict__ bias, u16* __restrict__ Y)
{
  __shared__ float As[16][64];  // transposed A tile: As[kk][m]
  __shared__ float Bs[16][64];
  const int tid = threadIdx.x;
  const int R0 = blockIdx.x * 64;
  const int N0 = blockIdx.y * 64;
  const int tx = tid & 15, ty = tid >> 4;
  const int am = tid >> 2, ak = (tid & 3) * 4;   // A staging
  const int bk = tid >> 4, bn = (tid & 15) * 4;  // B staging
  float acc[4][4] = {};

  for (int k0 = 0; k0 < H_DIM; k0 += 16) {
    const ushort4 a4 = *(const ushort4*)(X + (size_t)(R0 + am) * H_DIM + k0 + ak);
    const float4 b4 = *(const float4*)(Wt + (size_t)(k0 + bk) * H_DIM + N0 + bn);
    As[ak + 0][am] = b2f(a4.x); As[ak + 1][am] = b2f(a4.y);
    As[ak + 2][am] = b2f(a4.z); As[ak + 3][am] = b2f(a4.w);
    *(float4*)&Bs[bk][bn] = b4;
    __syncthreads();
#pragma unroll
    for (int kk = 0; kk < 16; ++kk) {
      const float4 av = *(const float4*)&As[kk][ty * 4];
      const float4 bv = *(const float4*)&Bs[kk][tx * 4];
      const float a[4] = {av.x, av.y, av.z, av.w};
      const float b[4] = {bv.x, bv.y, bv.z, bv.w};
#pragma unroll
      for (int mi = 0; mi < 4; ++mi)
#pragma unroll
        for (int ni = 0; ni < 4; ++ni)
          acc[mi][ni] = fmaf(a[mi], b[ni], acc[mi][ni]);
    }
    __syncthreads();
  }
  const float4 bv4 = *(const float4*)(bias + N0 + tx * 4);
#pragma unroll
  for (int mi = 0; mi < 4; ++mi) {
    ushort4 st;
    st.x = f2b(acc[mi][0] + bv4.x);
    st.y = f2b(acc[mi][1] + bv4.y);
    st.z = f2b(acc[mi][2] + bv4.z);
    st.w = f2b(acc[mi][3] + bv4.w);
    *(ushort4*)(Y + (size_t)(R0 + ty * 4 + mi) * H_DIM + N0 + tx * 4) = st;
  }
}

// ---------------------------------------------------------------------------
// 3b) in-place LayerNorm + ReLU over bf16 rows of Y (block = row).
// ---------------------------------------------------------------------------
__global__ __launch_bounds__(256) void ddsp_ln_relu(
    u16* __restrict__ Y, const float* __restrict__ scale, const float* __restrict__ bias)
{
  __shared__ float wsum[4], wsq[4];
  const int row = blockIdx.x, tid = threadIdx.x;
  const ushort4 r4 = *(const ushort4*)(Y + (size_t)row * H_DIM + tid * 4);
  float x[4] = {b2f(r4.x), b2f(r4.y), b2f(r4.z), b2f(r4.w)};
  float s = x[0] + x[1] + x[2] + x[3];
  float q = x[0] * x[0] + x[1] * x[1] + x[2] * x[2] + x[3] * x[3];
#pragma unroll
  for (int off = 32; off >= 1; off >>= 1) {
    s += __shfl_down(s, off);
    q += __shfl_down(q, off);
  }
  if ((tid & 63) == 0) { wsum[tid >> 6] = s; wsq[tid >> 6] = q; }
  __syncthreads();
  const float ts = wsum[0] + wsum[1] + wsum[2] + wsum[3];
  const float tq = wsq[0] + wsq[1] + wsq[2] + wsq[3];
  const float mu = ts * (1.0f / H_DIM);
  const float var = tq * (1.0f / H_DIM) - mu * mu;
  const float rstd = rsqrtf(fmaxf(var, 0.f) + 1e-6f);
  const float4 sc = *(const float4*)(scale + tid * 4);
  const float4 bi = *(const float4*)(bias + tid * 4);
  ushort4 st;
  st.x = f2b(fmaxf((x[0] - mu) * rstd * sc.x + bi.x, 0.f));
  st.y = f2b(fmaxf((x[1] - mu) * rstd * sc.y + bi.y, 0.f));
  st.z = f2b(fmaxf((x[2] - mu) * rstd * sc.z + bi.z, 0.f));
  st.w = f2b(fmaxf((x[3] - mu) * rstd * sc.w + bi.w, 0.f));
  *(ushort4*)(Y + (size_t)row * H_DIM + tid * 4) = st;
}

// ---------------------------------------------------------------------------
// 4) heads: block = timestep. threads 0..99 harm, 100..164 noise, 165 amp.
//    Hf is bf16; weights/bias/output f32.
// ---------------------------------------------------------------------------
__global__ __launch_bounds__(256) void ddsp_heads(
    const u16* __restrict__ Hf,
    const float* __restrict__ aW, const float* __restrict__ ab,
    const float* __restrict__ hW, const float* __restrict__ hb,
    const float* __restrict__ nW, const float* __restrict__ nb,
    float* __restrict__ out)
{
  __shared__ float lh[H_DIM];
  __shared__ float se[128];
  __shared__ float sred[2];  // [0]=amp, [1]=harm sum
  const int t = blockIdx.x, tid = threadIdx.x;
  const ushort4 h4 = *(const ushort4*)(Hf + (size_t)t * H_DIM + tid * 4);
  lh[tid * 4 + 0] = b2f(h4.x); lh[tid * 4 + 1] = b2f(h4.y);
  lh[tid * 4 + 2] = b2f(h4.z); lh[tid * 4 + 3] = b2f(h4.w);
  __syncthreads();

  if (tid < NHARM) {
    float acc = 0.f;
    for (int k = 0; k < H_DIM; k += 4) {
      const float4 hv = *(const float4*)(lh + k);
      acc = fmaf(hv.x, hW[(k + 0) * NHARM + tid], acc);
      acc = fmaf(hv.y, hW[(k + 1) * NHARM + tid], acc);
      acc = fmaf(hv.z, hW[(k + 2) * NHARM + tid], acc);
      acc = fmaf(hv.w, hW[(k + 3) * NHARM + tid], acc);
    }
    se[tid] = exp_sig(acc + hb[tid]);
  } else if (tid < NHARM + NNOISE) {
    const int n = tid - NHARM;
    float acc = 0.f;
    for (int k = 0; k < H_DIM; k += 4) {
      const float4 hv = *(const float4*)(lh + k);
      acc = fmaf(hv.x, nW[(k + 0) * NNOISE + n], acc);
      acc = fmaf(hv.y, nW[(k + 1) * NNOISE + n], acc);
      acc = fmaf(hv.z, nW[(k + 2) * NNOISE + n], acc);
      acc = fmaf(hv.w, nW[(k + 3) * NNOISE + n], acc);
    }
    out[(size_t)T_STEPS * NHARM + (size_t)t * NNOISE + n] = acc + nb[n];
  } else if (tid == NHARM + NNOISE) {
    float acc = 0.f;
    for (int k = 0; k < H_DIM; k += 4) {
      const float4 hv = *(const float4*)(lh + k);
      acc = fmaf(hv.x, aW[k + 0], acc);
      acc = fmaf(hv.y, aW[k + 1], acc);
      acc = fmaf(hv.z, aW[k + 2], acc);
      acc = fmaf(hv.w, aW[k + 3], acc);
    }
    sred[0] = exp_sig(acc + ab[0]);
  }
  if (tid >= NHARM && tid < 128) se[tid] = 0.f;  // pad for reduce
  __syncthreads();
  if (tid < 64) {
    float s2 = se[tid] + se[tid + 64];
#pragma unroll
    for (int off = 32; off >= 1; off >>= 1) s2 += __shfl_down(s2, off);
    if (tid == 0) sred[1] = s2;
  }
  __syncthreads();
  if (tid < NHARM) {
    out[(size_t)t * NHARM + tid] = sred[0] * se[tid] / (sred[1] + 1e-8f);
  }
}

// ---------------------------------------------------------------------------
extern "C" void kernel_launch(void* const* d_in, const int* in_sizes, int n_in,
                              void* d_out, int out_size, void* d_ws, size_t ws_size,
                              hipStream_t stream)
{
  (void)in_sizes; (void)n_in; (void)out_size;
  const float* f0   = (const float*)d_in[0];
  const float* loud = (const float*)d_in[1];
  const float* Win  = (const float*)d_in[2];
  const float* bin  = (const float*)d_in[3];
  const float* Wi   = (const float*)d_in[4];
  const float* Wh   = (const float*)d_in[5];
  const float* bh   = (const float*)d_in[6];
  const float* h0   = (const float*)d_in[7];
  const float* mlpW = (const float*)d_in[8];
  const float* mlpb = (const float*)d_in[9];
  const float* lnS  = (const float*)d_in[10];
  const float* lnB  = (const float*)d_in[11];
  const float* aW   = (const float*)d_in[12];
  const float* ab   = (const float*)d_in[13];
  const float* hW   = (const float*)d_in[14];
  const float* hb   = (const float*)d_in[15];
  const float* nW   = (const float*)d_in[16];
  const float* nb   = (const float*)d_in[17];
  float* out = (float*)d_out;

  char* ws = (char*)d_ws;
  float*    U     = (float*)(ws);                    // 3072 f32
  float*    V     = (float*)(ws + 12288);            // 3072 f32
  float*    Wc    = (float*)(ws + 24576);            // 3072 f32
  float*    hbuf  = (float*)(ws + 36864);            // 2 x 1024 f32
  unsigned* flags = (unsigned*)(ws + 45056);         // 128 u32 barrier flags
  u16* bufA = (u16*)(ws + 45568);                               // [T,H] bf16
  u16* bufB = (u16*)(ws + 45568 + (size_t)T_STEPS * H_DIM * 2); // [T,H] bf16

  const size_t needed = 45568 + 2 * (size_t)T_STEPS * H_DIM * 2;  // ~134.3 MB
  if (ws_size < needed) {
    // Workspace too small: do nothing -> bench reports absmax == max|ref|,
    // telling us ws_size is the constraint (vs a kernel fault).
    return;
  }

  ddsp_precompute<<<16, 256, 0, stream>>>(Win, bin, Wi, h0, U, V, Wc, hbuf, flags);
  ddsp_gru<<<GRU_NB, 256, 0, stream>>>(f0, loud, Wh, bh, U, V, Wc, hbuf, flags, bufA);

  dim3 gg(T_STEPS / 64, H_DIM / 64);
  ddsp_gemm_bias<<<gg, 256, 0, stream>>>(bufA, mlpW, mlpb, bufB);
  ddsp_ln_relu<<<T_STEPS, 256, 0, stream>>>(bufB, lnS, lnB);
  ddsp_gemm_bias<<<gg, 256, 0, stream>>>(bufB, mlpW + (size_t)H_DIM * H_DIM, mlpb + H_DIM, bufA);
  ddsp_ln_relu<<<T_STEPS, 256, 0, stream>>>(bufA, lnS + H_DIM, lnB + H_DIM);
  ddsp_gemm_bias<<<gg, 256, 0, stream>>>(bufA, mlpW + 2 * (size_t)H_DIM * H_DIM, mlpb + 2 * H_DIM, bufB);
  ddsp_ln_relu<<<T_STEPS, 256, 0, stream>>>(bufB, lnS + 2 * H_DIM, lnB + 2 * H_DIM);

  ddsp_heads<<<T_STEPS, 256, 0, stream>>>(bufB, aW, ab, hW, hb, nW, nb, out);
}

// Round 7
// 117140.186 us; speedup vs baseline: 2.3430x; 1.7450x over previous
//
#include <hip/hip_runtime.h>
#include <cstdint>
#include <cmath>

// ---------------------------------------------------------------------------
// DDSP decoder on MI355X — inputs/outputs float32 (per reference dtypes).
//   1) precompute: gi_t = f0_t*U + loud_t*V + W  (input GEMM is rank-2+const)
//   2) persistent GRU: 128 blocks x 256 thr; Wh slice (8 cols x 3 gates, f32)
//      staged in LDS (96 KB). Fence-free barrier (r5: agent fences = L2
//      writeback storm). r6 post-mortem: all-poll-all barrier = 16K concurrent
//      uncached loads on 2 cachelines/step -> LLC slice serialization ~16K cy.
//      r7: master-broadcast barrier (block0 polls 64B-strided flags, bumps
//      replicated epoch; others poll one epoch replica), dwordx4 bypass
//      h reload. Cross-block words only ever touched by cache-bypass ops.
//   3) 3x (64x64-tile GEMM bf16-in/f32-acc/bf16-out + bias) + LN+ReLU.
//   4) heads: per-t block; amp/harm/noise projections, exp_sigmoid, normalize.
// ---------------------------------------------------------------------------

#define T_STEPS 32768
#define H_DIM   1024
#define H3      3072
#define NHARM   100
#define NNOISE  65
#define GRU_NB  128
#define GRU_CPB 8      // columns (h outputs) per block

typedef unsigned short u16;

__device__ __forceinline__ float b2f(u16 u) {
  union { unsigned u; float f; } x; x.u = ((unsigned)u) << 16; return x.f;
}
__device__ __forceinline__ u16 f2b(float f) {
  unsigned v = __float_as_uint(f);
  unsigned r = (v + 0x7FFFu + ((v >> 16) & 1u)) >> 16;  // RNE
  return (u16)r;
}
__device__ __forceinline__ float sigm(float x) { return 1.0f / (1.0f + expf(-x)); }
__device__ __forceinline__ float exp_sig(float x) {
  // 2.0 * sigmoid(x)^ln(10) + 1e-7
  float s = sigm(x);
  return 2.0f * expf(2.302585093f * logf(s)) + 1e-7f;
}

// 16B cache-bypassing load (system-scope sc0 sc1 -> skips L1/L2; reads the
// coherence point). One line-access per thread instead of 4 scalar dwords.
__device__ __forceinline__ float4 bypass_load_f4(const float* p) {
  float4 r;
  asm volatile("global_load_dwordx4 %0, %1, off sc0 sc1\n\t"
               "s_waitcnt vmcnt(0)"
               : "=v"(r) : "v"(p) : "memory");
  return r;
}

// ---------------------------------------------------------------------------
// 1) U[j] = sum_h Win[0,h]*Wi[h,j]; V[j] = sum_h Win[1,h]*Wi[h,j];
//    W[j] = sum_h bin[h]*Wi[h,j].  Blocks 12..15 init h-buffer+flags+epoch.
//    (plain stores OK: kernel-end release flushes L2 before the GRU launch)
// ---------------------------------------------------------------------------
__global__ __launch_bounds__(256) void ddsp_precompute(
    const float* __restrict__ Win, const float* __restrict__ bin,
    const float* __restrict__ Wi, const float* __restrict__ h0,
    float* __restrict__ U, float* __restrict__ V, float* __restrict__ Wc,
    float* __restrict__ hbuf, unsigned* __restrict__ flags,
    unsigned* __restrict__ epoch)
{
  const int gid = blockIdx.x * 256 + threadIdx.x;
  if (blockIdx.x < 12) {
    const int j = gid;  // 0..3071
    float su = 0.f, sv = 0.f, sw = 0.f;
    for (int h = 0; h < H_DIM; ++h) {
      const float wv = Wi[h * H3 + j];        // lanes j consecutive -> coalesced
      su = fmaf(Win[h], wv, su);
      sv = fmaf(Win[H_DIM + h], wv, sv);
      sw = fmaf(bin[h], wv, sw);
    }
    U[j] = su; V[j] = sv; Wc[j] = sw;
  } else {
    const int idx = gid - 12 * 256;           // 0..1023
    hbuf[idx] = h0[idx];
    flags[idx] = 0u;                          // ws poisoned 0xAA -> must init
    flags[idx + 1024] = 0u;                   // flags = 128 x 16 u32 (64B stride)
    if (idx < 128) epoch[idx] = 0u;           // epoch = 8 x 16 u32 replicas
  }
}

// ---------------------------------------------------------------------------
// 2) persistent GRU.  128 blocks x 256 thr.  thread = (jl = tid>>5 col 0..7,
//    i = tid&31 k-chunk).  Wh slice [3][8][1024] f32 staged in LDS once.
//    Per step: dwordx4 bypass h reload -> LDS, 32 ds_read_b128 + 96 FMA per
//    thread, 32-lane butterfly reduce, gate math on i==0, then the
//    master-broadcast fence-free barrier (see header comment).
// ---------------------------------------------------------------------------
__global__ __launch_bounds__(256, 1) void ddsp_gru(
    const float* __restrict__ f0, const float* __restrict__ loud,
    const float* __restrict__ Wh, const float* __restrict__ bh,
    const float* __restrict__ U, const float* __restrict__ V,
    const float* __restrict__ Wc,
    float* __restrict__ hbuf, unsigned* __restrict__ flags,
    unsigned* __restrict__ epoch, u16* __restrict__ hall)
{
  __shared__ float wlds[3 * GRU_CPB * H_DIM];  // 96 KB: [g][c][k]
  __shared__ float lds_h[H_DIM];               // 4 KB
  const int tid = threadIdx.x;
  const int i  = tid & 31;
  const int jl = tid >> 5;
  const int jg = blockIdx.x * GRU_CPB + jl;

  // One-time LDS weight stage: wlds[g][c][k] = Wh[k][g*1024 + block*8 + c].
  for (int g = 0; g < 3; ++g) {
    for (int c = 0; c < GRU_CPB; ++c) {
      const int col = g * H_DIM + blockIdx.x * GRU_CPB + c;
#pragma unroll
      for (int e = 0; e < 4; ++e) {
        const int k = tid * 4 + e;
        wlds[(g * GRU_CPB + c) * H_DIM + k] = Wh[(size_t)k * H3 + col];
      }
    }
  }

  float ur = 0.f, uz = 0.f, un = 0.f, vr = 0.f, vz = 0.f, vn = 0.f;
  float wr = 0.f, wz = 0.f, wn = 0.f, bhr = 0.f, bhz = 0.f, bhn = 0.f;
  if (i == 0) {
    ur = U[jg]; uz = U[jg + 1024]; un = U[jg + 2048];
    vr = V[jg]; vz = V[jg + 1024]; vn = V[jg + 2048];
    wr = Wc[jg]; wz = Wc[jg + 1024]; wn = Wc[jg + 2048];
    bhr = bh[jg]; bhz = bh[jg + 1024]; bhn = bh[jg + 2048];
  }
  __syncthreads();

  const float* wl0 = wlds + (0 * GRU_CPB + jl) * H_DIM;
  const float* wl1 = wlds + (1 * GRU_CPB + jl) * H_DIM;
  const float* wl2 = wlds + (2 * GRU_CPB + jl) * H_DIM;

  for (int t = 0; t < T_STEPS; ++t) {
    const float* hcur = hbuf + (t & 1) * H_DIM;
    float* hnxt = hbuf + ((t + 1) & 1) * H_DIM;

    // prefetch scalar inputs off the post-reduce critical path
    const float fv = f0[t];
    const float lv = loud[t];

    // stage h_t into LDS via one 16B cache-bypass load per thread
    const float4 hin = bypass_load_f4(hcur + tid * 4);
    *(float4*)(lds_h + tid * 4) = hin;
    __syncthreads();

    float a0 = 0.f, a1 = 0.f, a2 = 0.f;
    const int kbase = i << 5;  // i*32
#pragma unroll
    for (int it = 0; it < 8; ++it) {
      const int kk = kbase + (((it + i) & 7) << 2);  // rotation spreads banks
      const float4 h4 = *(const float4*)(lds_h + kk);
      const float4 wa = *(const float4*)(wl0 + kk);
      const float4 wb = *(const float4*)(wl1 + kk);
      const float4 wc4 = *(const float4*)(wl2 + kk);
      a0 = fmaf(wa.x, h4.x, a0); a0 = fmaf(wa.y, h4.y, a0);
      a0 = fmaf(wa.z, h4.z, a0); a0 = fmaf(wa.w, h4.w, a0);
      a1 = fmaf(wb.x, h4.x, a1); a1 = fmaf(wb.y, h4.y, a1);
      a1 = fmaf(wb.z, h4.z, a1); a1 = fmaf(wb.w, h4.w, a1);
      a2 = fmaf(wc4.x, h4.x, a2); a2 = fmaf(wc4.y, h4.y, a2);
      a2 = fmaf(wc4.z, h4.z, a2); a2 = fmaf(wc4.w, h4.w, a2);
    }
    // butterfly reduce over the 32-lane group
#pragma unroll
    for (int m = 1; m < 32; m <<= 1) {
      a0 += __shfl_xor(a0, m);
      a1 += __shfl_xor(a1, m);
      a2 += __shfl_xor(a2, m);
    }
    if (i == 0) {
      const float gir = fmaf(fv, ur, fmaf(lv, vr, wr));
      const float giz = fmaf(fv, uz, fmaf(lv, vz, wz));
      const float gin = fmaf(fv, un, fmaf(lv, vn, wn));
      const float r = sigm(gir + a0 + bhr);
      const float z = sigm(giz + a1 + bhz);
      const float n = tanhf(fmaf(r, a2 + bhn, gin));  // b_h[n] inside r*( )
      const float hp = lds_h[jg];
      const float hn = (1.0f - z) * n + z * hp;
      __hip_atomic_store(hnxt + jg, hn, __ATOMIC_RELAXED, __HIP_MEMORY_SCOPE_AGENT);
      hall[(size_t)t * H_DIM + jg] = f2b(hn);
    }
    // Drain this wave's bypass stores, then block barrier.
    asm volatile("s_waitcnt vmcnt(0)" ::: "memory");
    __syncthreads();

    const unsigned tgt = (unsigned)(t + 1);
    if (blockIdx.x == 0) {
      // master: wave 0 polls flags of blocks 1..127 (64B-strided -> spread
      // across LLC slices), then bumps the 8 epoch replicas.
      if (tid < 64) {
        const int b1 = 2 * tid + 1;
        const int b2 = 2 * tid + 2;
        bool ok;
        do {
          const unsigned fa = __hip_atomic_load(&flags[b1 * 16],
                                                __ATOMIC_RELAXED, __HIP_MEMORY_SCOPE_AGENT);
          const unsigned fb = (b2 < GRU_NB)
              ? __hip_atomic_load(&flags[b2 * 16],
                                  __ATOMIC_RELAXED, __HIP_MEMORY_SCOPE_AGENT)
              : tgt;
          ok = (fa >= tgt) && (fb >= tgt);
        } while (!__all(ok));
        if (tid < 8) {
          __hip_atomic_store(&epoch[tid * 16], tgt,
                             __ATOMIC_RELAXED, __HIP_MEMORY_SCOPE_AGENT);
        }
      }
    } else {
      // arrive (flag store ordered after h stores by the vmcnt drain above),
      // then one lane polls one epoch replica.
      if (tid == 0) {
        __hip_atomic_store(&flags[blockIdx.x * 16], tgt,
                           __ATOMIC_RELAXED, __HIP_MEMORY_SCOPE_AGENT);
        unsigned e;
        do {
          e = __hip_atomic_load(&epoch[(blockIdx.x & 7) * 16],
                                __ATOMIC_RELAXED, __HIP_MEMORY_SCOPE_AGENT);
        } while (e < tgt);
      }
    }
    asm volatile("" ::: "memory");  // compiler ordering pin (no HW op)
    __syncthreads();
  }
}

// ---------------------------------------------------------------------------
// 3a) Y[T,1024](bf16) = X[T,1024](bf16) @ W[1024,1024](f32) + bias(f32)
//     64x64 tile, 256 thr, 4x4 micro-tile, K-step 16, f32 accumulate.
// ---------------------------------------------------------------------------
__global__ __launch_bounds__(256) void ddsp_gemm_bias(
    const u16* __restrict__ X, const float* __restrict__ Wt,
    const float* __restrict__ bias, u16* __restrict__ Y)
{
  __shared__ float As[16][64];  // transposed A tile: As[kk][m]
  __shared__ float Bs[16][64];
  const int tid = threadIdx.x;
  const int R0 = blockIdx.x * 64;
  const int N0 = blockIdx.y * 64;
  const int tx = tid & 15, ty = tid >> 4;
  const int am = tid >> 2, ak = (tid & 3) * 4;   // A staging
  const int bk = tid >> 4, bn = (tid & 15) * 4;  // B staging
  float acc[4][4] = {};

  for (int k0 = 0; k0 < H_DIM; k0 += 16) {
    const ushort4 a4 = *(const ushort4*)(X + (size_t)(R0 + am) * H_DIM + k0 + ak);
    const float4 b4 = *(const float4*)(Wt + (size_t)(k0 + bk) * H_DIM + N0 + bn);
    As[ak + 0][am] = b2f(a4.x); As[ak + 1][am] = b2f(a4.y);
    As[ak + 2][am] = b2f(a4.z); As[ak + 3][am] = b2f(a4.w);
    *(float4*)&Bs[bk][bn] = b4;
    __syncthreads();
#pragma unroll
    for (int kk = 0; kk < 16; ++kk) {
      const float4 av = *(const float4*)&As[kk][ty * 4];
      const float4 bv = *(const float4*)&Bs[kk][tx * 4];
      const float a[4] = {av.x, av.y, av.z, av.w};
      const float b[4] = {bv.x, bv.y, bv.z, bv.w};
#pragma unroll
      for (int mi = 0; mi < 4; ++mi)
#pragma unroll
        for (int ni = 0; ni < 4; ++ni)
          acc[mi][ni] = fmaf(a[mi], b[ni], acc[mi][ni]);
    }
    __syncthreads();
  }
  const float4 bv4 = *(const float4*)(bias + N0 + tx * 4);
#pragma unroll
  for (int mi = 0; mi < 4; ++mi) {
    ushort4 st;
    st.x = f2b(acc[mi][0] + bv4.x);
    st.y = f2b(acc[mi][1] + bv4.y);
    st.z = f2b(acc[mi][2] + bv4.z);
    st.w = f2b(acc[mi][3] + bv4.w);
    *(ushort4*)(Y + (size_t)(R0 + ty * 4 + mi) * H_DIM + N0 + tx * 4) = st;
  }
}

// ---------------------------------------------------------------------------
// 3b) in-place LayerNorm + ReLU over bf16 rows of Y (block = row).
// ---------------------------------------------------------------------------
__global__ __launch_bounds__(256) void ddsp_ln_relu(
    u16* __restrict__ Y, const float* __restrict__ scale, const float* __restrict__ bias)
{
  __shared__ float wsum[4], wsq[4];
  const int row = blockIdx.x, tid = threadIdx.x;
  const ushort4 r4 = *(const ushort4*)(Y + (size_t)row * H_DIM + tid * 4);
  float x[4] = {b2f(r4.x), b2f(r4.y), b2f(r4.z), b2f(r4.w)};
  float s = x[0] + x[1] + x[2] + x[3];
  float q = x[0] * x[0] + x[1] * x[1] + x[2] * x[2] + x[3] * x[3];
#pragma unroll
  for (int off = 32; off >= 1; off >>= 1) {
    s += __shfl_down(s, off);
    q += __shfl_down(q, off);
  }
  if ((tid & 63) == 0) { wsum[tid >> 6] = s; wsq[tid >> 6] = q; }
  __syncthreads();
  const float ts = wsum[0] + wsum[1] + wsum[2] + wsum[3];
  const float tq = wsq[0] + wsq[1] + wsq[2] + wsq[3];
  const float mu = ts * (1.0f / H_DIM);
  const float var = tq * (1.0f / H_DIM) - mu * mu;
  const float rstd = rsqrtf(fmaxf(var, 0.f) + 1e-6f);
  const float4 sc = *(const float4*)(scale + tid * 4);
  const float4 bi = *(const float4*)(bias + tid * 4);
  ushort4 st;
  st.x = f2b(fmaxf((x[0] - mu) * rstd * sc.x + bi.x, 0.f));
  st.y = f2b(fmaxf((x[1] - mu) * rstd * sc.y + bi.y, 0.f));
  st.z = f2b(fmaxf((x[2] - mu) * rstd * sc.z + bi.z, 0.f));
  st.w = f2b(fmaxf((x[3] - mu) * rstd * sc.w + bi.w, 0.f));
  *(ushort4*)(Y + (size_t)row * H_DIM + tid * 4) = st;
}

// ---------------------------------------------------------------------------
// 4) heads: block = timestep. threads 0..99 harm, 100..164 noise, 165 amp.
//    Hf is bf16; weights/bias/output f32.
// ---------------------------------------------------------------------------
__global__ __launch_bounds__(256) void ddsp_heads(
    const u16* __restrict__ Hf,
    const float* __restrict__ aW, const float* __restrict__ ab,
    const float* __restrict__ hW, const float* __restrict__ hb,
    const float* __restrict__ nW, const float* __restrict__ nb,
    float* __restrict__ out)
{
  __shared__ float lh[H_DIM];
  __shared__ float se[128];
  __shared__ float sred[2];  // [0]=amp, [1]=harm sum
  const int t = blockIdx.x, tid = threadIdx.x;
  const ushort4 h4 = *(const ushort4*)(Hf + (size_t)t * H_DIM + tid * 4);
  lh[tid * 4 + 0] = b2f(h4.x); lh[tid * 4 + 1] = b2f(h4.y);
  lh[tid * 4 + 2] = b2f(h4.z); lh[tid * 4 + 3] = b2f(h4.w);
  __syncthreads();

  if (tid < NHARM) {
    float acc = 0.f;
    for (int k = 0; k < H_DIM; k += 4) {
      const float4 hv = *(const float4*)(lh + k);
      acc = fmaf(hv.x, hW[(k + 0) * NHARM + tid], acc);
      acc = fmaf(hv.y, hW[(k + 1) * NHARM + tid], acc);
      acc = fmaf(hv.z, hW[(k + 2) * NHARM + tid], acc);
      acc = fmaf(hv.w, hW[(k + 3) * NHARM + tid], acc);
    }
    se[tid] = exp_sig(acc + hb[tid]);
  } else if (tid < NHARM + NNOISE) {
    const int n = tid - NHARM;
    float acc = 0.f;
    for (int k = 0; k < H_DIM; k += 4) {
      const float4 hv = *(const float4*)(lh + k);
      acc = fmaf(hv.x, nW[(k + 0) * NNOISE + n], acc);
      acc = fmaf(hv.y, nW[(k + 1) * NNOISE + n], acc);
      acc = fmaf(hv.z, nW[(k + 2) * NNOISE + n], acc);
      acc = fmaf(hv.w, nW[(k + 3) * NNOISE + n], acc);
    }
    out[(size_t)T_STEPS * NHARM + (size_t)t * NNOISE + n] = acc + nb[n];
  } else if (tid == NHARM + NNOISE) {
    float acc = 0.f;
    for (int k = 0; k < H_DIM; k += 4) {
      const float4 hv = *(const float4*)(lh + k);
      acc = fmaf(hv.x, aW[k + 0], acc);
      acc = fmaf(hv.y, aW[k + 1], acc);
      acc = fmaf(hv.z, aW[k + 2], acc);
      acc = fmaf(hv.w, aW[k + 3], acc);
    }
    sred[0] = exp_sig(acc + ab[0]);
  }
  if (tid >= NHARM && tid < 128) se[tid] = 0.f;  // pad for reduce
  __syncthreads();
  if (tid < 64) {
    float s2 = se[tid] + se[tid + 64];
#pragma unroll
    for (int off = 32; off >= 1; off >>= 1) s2 += __shfl_down(s2, off);
    if (tid == 0) sred[1] = s2;
  }
  __syncthreads();
  if (tid < NHARM) {
    out[(size_t)t * NHARM + tid] = sred[0] * se[tid] / (sred[1] + 1e-8f);
  }
}

// ---------------------------------------------------------------------------
extern "C" void kernel_launch(void* const* d_in, const int* in_sizes, int n_in,
                              void* d_out, int out_size, void* d_ws, size_t ws_size,
                              hipStream_t stream)
{
  (void)in_sizes; (void)n_in; (void)out_size;
  const float* f0   = (const float*)d_in[0];
  const float* loud = (const float*)d_in[1];
  const float* Win  = (const float*)d_in[2];
  const float* bin  = (const float*)d_in[3];
  const float* Wi   = (const float*)d_in[4];
  const float* Wh   = (const float*)d_in[5];
  const float* bh   = (const float*)d_in[6];
  const float* h0   = (const float*)d_in[7];
  const float* mlpW = (const float*)d_in[8];
  const float* mlpb = (const float*)d_in[9];
  const float* lnS  = (const float*)d_in[10];
  const float* lnB  = (const float*)d_in[11];
  const float* aW   = (const float*)d_in[12];
  const float* ab   = (const float*)d_in[13];
  const float* hW   = (const float*)d_in[14];
  const float* hb   = (const float*)d_in[15];
  const float* nW   = (const float*)d_in[16];
  const float* nb   = (const float*)d_in[17];
  float* out = (float*)d_out;

  char* ws = (char*)d_ws;
  float*    U     = (float*)(ws);                    // 3072 f32
  float*    V     = (float*)(ws + 12288);            // 3072 f32
  float*    Wc    = (float*)(ws + 24576);            // 3072 f32
  float*    hbuf  = (float*)(ws + 36864);            // 2 x 1024 f32
  unsigned* flags = (unsigned*)(ws + 45056);         // 128 x 16 u32 (64B stride)
  unsigned* epoch = (unsigned*)(ws + 53248);         // 8 x 16 u32 replicas
  u16* bufA = (u16*)(ws + 53760);                               // [T,H] bf16
  u16* bufB = (u16*)(ws + 53760 + (size_t)T_STEPS * H_DIM * 2); // [T,H] bf16

  const size_t needed = 53760 + 2 * (size_t)T_STEPS * H_DIM * 2;  // ~134.3 MB
  if (ws_size < needed) {
    // Workspace too small: do nothing -> bench reports absmax == max|ref|.
    return;
  }

  ddsp_precompute<<<16, 256, 0, stream>>>(Win, bin, Wi, h0, U, V, Wc, hbuf, flags, epoch);
  ddsp_gru<<<GRU_NB, 256, 0, stream>>>(f0, loud, Wh, bh, U, V, Wc, hbuf, flags, epoch, bufA);

  dim3 gg(T_STEPS / 64, H_DIM / 64);
  ddsp_gemm_bias<<<gg, 256, 0, stream>>>(bufA, mlpW, mlpb, bufB);
  ddsp_ln_relu<<<T_STEPS, 256, 0, stream>>>(bufB, lnS, lnB);
  ddsp_gemm_bias<<<gg, 256, 0, stream>>>(bufB, mlpW + (size_t)H_DIM * H_DIM, mlpb + H_DIM, bufA);
  ddsp_ln_relu<<<T_STEPS, 256, 0, stream>>>(bufA, lnS + H_DIM, lnB + H_DIM);
  ddsp_gemm_bias<<<gg, 256, 0, stream>>>(bufA, mlpW + 2 * (size_t)H_DIM * H_DIM, mlpb + 2 * H_DIM, bufB);
  ddsp_ln_relu<<<T_STEPS, 256, 0, stream>>>(bufB, lnS + 2 * H_DIM, lnB + 2 * H_DIM);

  ddsp_heads<<<T_STEPS, 256, 0, stream>>>(bufB, aW, ab, hW, hb, nW, nb, out);
}

// Round 9
// 115619.836 us; speedup vs baseline: 2.3738x; 1.0131x over previous
//
#include <hip/hip_runtime.h>
#include <cstdint>
#include <cmath>

// ---------------------------------------------------------------------------
// DDSP decoder on MI355X — inputs/outputs float32 (per reference dtypes).
//   1) precompute: gi_t = f0_t*U + loud_t*V + W  (input GEMM is rank-2+const)
//   2) persistent GRU: 128 blocks x 256 thr; Wh slice (8 cols x 3 gates, f32)
//      in LDS (96 KB). r8/r9: FUSED h-exchange+barrier — each block publishes
//      its 8 h values into its own 64B cacheline slot with a tag in each 16B
//      quad (tag==step validates the quad's data; no tearing, no fences).
//      Double-buffered slot sets by step parity (overwrite-safety by
//      induction: reaching t+2 requires seeing all t+1 tags, which requires
//      all blocks done reading parity-t). ONE LLC round trip per step vs 3 in
//      r7 (h store->flag->epoch->h load). History: r5 fences = L2 writeback
//      storm; r6 all-poll-all = LLC line contention; r7 = master-broadcast.
//      r9 fix: inline-asm store data must be ext_vector_type, not uint4
//      (LLVM rejects aggregate inputs for 'v'; outputs were fine).
//   3) 3x (64x64-tile GEMM bf16-in/f32-acc/bf16-out + bias) + LN+ReLU.
//   4) heads: per-t block; amp/harm/noise projections, exp_sigmoid, normalize.
// ---------------------------------------------------------------------------

#define T_STEPS 32768
#define H_DIM   1024
#define H3      3072
#define NHARM   100
#define NNOISE  65
#define GRU_NB  128
#define GRU_CPB 8      // columns (h outputs) per block

typedef unsigned short u16;
typedef unsigned uv4 __attribute__((ext_vector_type(4)));

__device__ __forceinline__ float b2f(u16 u) {
  union { unsigned u; float f; } x; x.u = ((unsigned)u) << 16; return x.f;
}
__device__ __forceinline__ u16 f2b(float f) {
  unsigned v = __float_as_uint(f);
  unsigned r = (v + 0x7FFFu + ((v >> 16) & 1u)) >> 16;  // RNE
  return (u16)r;
}
__device__ __forceinline__ float sigm(float x) { return 1.0f / (1.0f + expf(-x)); }
__device__ __forceinline__ float exp_sig(float x) {
  // 2.0 * sigmoid(x)^ln(10) + 1e-7
  float s = sigm(x);
  return 2.0f * expf(2.302585093f * logf(s)) + 1e-7f;
}

// 48B cache-bypassing line read (3 dwordx4 issued back-to-back, one drain):
// one LLC access latency for tag-check AND data.
__device__ __forceinline__ void bypass_load_3x4(const unsigned* p,
                                                uv4& a, uv4& b, uv4& c) {
  asm volatile("global_load_dwordx4 %0, %3, off sc0 sc1\n\t"
               "global_load_dwordx4 %1, %3, off offset:16 sc0 sc1\n\t"
               "global_load_dwordx4 %2, %3, off offset:32 sc0 sc1\n\t"
               "s_waitcnt vmcnt(0)"
               : "=v"(a), "=v"(b), "=v"(c) : "v"(p) : "memory");
}
__device__ __forceinline__ void bypass_store_x4(unsigned* p, uv4 v) {
  asm volatile("global_store_dwordx4 %0, %1, off sc0 sc1"
               :: "v"(p), "v"(v) : "memory");
}

// slots layout: 2 sets (step parity) x 128 lines x 16 u32 (64B).
// line = [tag,h0,h1,h2][tag,h3,h4,h5][tag,h6,h7,-][----]

// ---------------------------------------------------------------------------
// 1) U[j] = sum_h Win[0,h]*Wi[h,j]; V[j] = sum_h Win[1,h]*Wi[h,j];
//    W[j] = sum_h bin[h]*Wi[h,j].  Blocks 12..15: init h slot lines.
//    (plain stores: end-of-kernel release makes them device-visible)
// ---------------------------------------------------------------------------
__global__ __launch_bounds__(256) void ddsp_precompute(
    const float* __restrict__ Win, const float* __restrict__ bin,
    const float* __restrict__ Wi, const float* __restrict__ h0,
    float* __restrict__ U, float* __restrict__ V, float* __restrict__ Wc,
    unsigned* __restrict__ slots)
{
  const int gid = blockIdx.x * 256 + threadIdx.x;
  if (blockIdx.x < 12) {
    const int j = gid;  // 0..3071
    float su = 0.f, sv = 0.f, sw = 0.f;
    for (int h = 0; h < H_DIM; ++h) {
      const float wv = Wi[h * H3 + j];        // lanes j consecutive -> coalesced
      su = fmaf(Win[h], wv, su);
      sv = fmaf(Win[H_DIM + h], wv, sv);
      sw = fmaf(bin[h], wv, sw);
    }
    U[j] = su; V[j] = sv; Wc[j] = sw;
  } else {
    const int idx = gid - 12 * 256;           // 0..1023
    if (idx < GRU_NB) {
      unsigned* l0 = slots + idx * 16;            // parity-0 set: tag 0 + h0
      unsigned* l1 = slots + GRU_NB * 16 + idx * 16;  // parity-1 set
      l0[0] = 0u; l0[1] = __float_as_uint(h0[idx * 8 + 0]);
      l0[2] = __float_as_uint(h0[idx * 8 + 1]);
      l0[3] = __float_as_uint(h0[idx * 8 + 2]);
      l0[4] = 0u; l0[5] = __float_as_uint(h0[idx * 8 + 3]);
      l0[6] = __float_as_uint(h0[idx * 8 + 4]);
      l0[7] = __float_as_uint(h0[idx * 8 + 5]);
      l0[8] = 0u; l0[9] = __float_as_uint(h0[idx * 8 + 6]);
      l0[10] = __float_as_uint(h0[idx * 8 + 7]);
      l0[11] = 0u;
      l1[0] = 0u; l1[4] = 0u; l1[8] = 0u;     // != any odd tag (ws poisoned)
    }
  }
}

// ---------------------------------------------------------------------------
// 2) persistent GRU.  128 blocks x 256 thr.  thread = (jl = tid>>5 col 0..7,
//    i = tid&31 k-chunk).  Wh slice [3][8][1024] f32 staged in LDS once.
//    Per step: tid<128 poll+assemble h from slot lines (1 line each) -> LDS,
//    24 ds_read_b128 + 96 FMA per thread, 32-lane butterfly reduce, gates on
//    i==0 -> LDS gather, tid0 publishes the block's tagged line. hall history
//    store issued after publish so its ack drains during the next poll.
// ---------------------------------------------------------------------------
__global__ __launch_bounds__(256, 1) void ddsp_gru(
    const float* __restrict__ f0, const float* __restrict__ loud,
    const float* __restrict__ Wh, const float* __restrict__ bh,
    const float* __restrict__ U, const float* __restrict__ V,
    const float* __restrict__ Wc,
    unsigned* __restrict__ slots, u16* __restrict__ hall)
{
  __shared__ float wlds[3 * GRU_CPB * H_DIM];  // 96 KB: [g][c][k]
  __shared__ float lds_h[H_DIM];               // 4 KB
  __shared__ float lds_hout[GRU_CPB];
  const int tid = threadIdx.x;
  const int i  = tid & 31;
  const int jl = tid >> 5;
  const int jg = blockIdx.x * GRU_CPB + jl;

  // One-time LDS weight stage: wlds[g][c][k] = Wh[k][g*1024 + block*8 + c].
  for (int g = 0; g < 3; ++g) {
    for (int c = 0; c < GRU_CPB; ++c) {
      const int col = g * H_DIM + blockIdx.x * GRU_CPB + c;
#pragma unroll
      for (int e = 0; e < 4; ++e) {
        const int k = tid * 4 + e;
        wlds[(g * GRU_CPB + c) * H_DIM + k] = Wh[(size_t)k * H3 + col];
      }
    }
  }

  float ur = 0.f, uz = 0.f, un = 0.f, vr = 0.f, vz = 0.f, vn = 0.f;
  float wr = 0.f, wz = 0.f, wn = 0.f, bhr = 0.f, bhz = 0.f, bhn = 0.f;
  if (i == 0) {
    ur = U[jg]; uz = U[jg + 1024]; un = U[jg + 2048];
    vr = V[jg]; vz = V[jg + 1024]; vn = V[jg + 2048];
    wr = Wc[jg]; wz = Wc[jg + 1024]; wn = Wc[jg + 2048];
    bhr = bh[jg]; bhz = bh[jg + 1024]; bhn = bh[jg + 2048];
  }
  __syncthreads();

  const float* wl0 = wlds + (0 * GRU_CPB + jl) * H_DIM;
  const float* wl1 = wlds + (1 * GRU_CPB + jl) * H_DIM;
  const float* wl2 = wlds + (2 * GRU_CPB + jl) * H_DIM;

  for (int t = 0; t < T_STEPS; ++t) {
    const unsigned tag = (unsigned)t;
    unsigned* slot_rd = slots + (size_t)(t & 1) * GRU_NB * 16;
    unsigned* slot_wr = slots + (size_t)((t + 1) & 1) * GRU_NB * 16;

    // prefetch scalar inputs off the critical path
    const float fv = f0[t];
    const float lv = loud[t];

    // poll+assemble: thread tid owns line tid. tag==t in all 3 quads
    // validates the quads' data (written with the same store).
    if (tid < GRU_NB) {
      const unsigned* line = slot_rd + tid * 16;
      uv4 a, b, c;
      do {
        bypass_load_3x4(line, a, b, c);
      } while (a.x != tag || b.x != tag || c.x != tag);
      float4 hA, hB;
      hA.x = __uint_as_float(a.y); hA.y = __uint_as_float(a.z);
      hA.z = __uint_as_float(a.w); hA.w = __uint_as_float(b.y);
      hB.x = __uint_as_float(b.z); hB.y = __uint_as_float(b.w);
      hB.z = __uint_as_float(c.y); hB.w = __uint_as_float(c.z);
      *(float4*)(lds_h + tid * 8) = hA;
      *(float4*)(lds_h + tid * 8 + 4) = hB;
    }
    __syncthreads();

    float a0 = 0.f, a1 = 0.f, a2 = 0.f;
    const int kbase = i << 5;  // i*32
#pragma unroll
    for (int it = 0; it < 8; ++it) {
      const int kk = kbase + (((it + i) & 7) << 2);  // rotation spreads banks
      const float4 h4 = *(const float4*)(lds_h + kk);
      const float4 wa = *(const float4*)(wl0 + kk);
      const float4 wb = *(const float4*)(wl1 + kk);
      const float4 wc4 = *(const float4*)(wl2 + kk);
      a0 = fmaf(wa.x, h4.x, a0); a0 = fmaf(wa.y, h4.y, a0);
      a0 = fmaf(wa.z, h4.z, a0); a0 = fmaf(wa.w, h4.w, a0);
      a1 = fmaf(wb.x, h4.x, a1); a1 = fmaf(wb.y, h4.y, a1);
      a1 = fmaf(wb.z, h4.z, a1); a1 = fmaf(wb.w, h4.w, a1);
      a2 = fmaf(wc4.x, h4.x, a2); a2 = fmaf(wc4.y, h4.y, a2);
      a2 = fmaf(wc4.z, h4.z, a2); a2 = fmaf(wc4.w, h4.w, a2);
    }
    // butterfly reduce over the 32-lane group
#pragma unroll
    for (int m = 1; m < 32; m <<= 1) {
      a0 += __shfl_xor(a0, m);
      a1 += __shfl_xor(a1, m);
      a2 += __shfl_xor(a2, m);
    }
    float hn = 0.f;
    if (i == 0) {
      const float gir = fmaf(fv, ur, fmaf(lv, vr, wr));
      const float giz = fmaf(fv, uz, fmaf(lv, vz, wz));
      const float gin = fmaf(fv, un, fmaf(lv, vn, wn));
      const float r = sigm(gir + a0 + bhr);
      const float z = sigm(giz + a1 + bhz);
      const float n = tanhf(fmaf(r, a2 + bhn, gin));  // b_h[n] inside r*( )
      const float hp = lds_h[jg];
      hn = (1.0f - z) * n + z * hp;
      lds_hout[jl] = hn;
    }
    __syncthreads();

    // publish: tag t+1 embedded in every quad; parity double-buffer makes
    // the overwrite race-free (see header). No drain needed (self-validating).
    if (tid == 0) {
      const unsigned ntag = (unsigned)(t + 1);
      const float4 hA = *(const float4*)(lds_hout);
      const float4 hB = *(const float4*)(lds_hout + 4);
      unsigned* line = slot_wr + blockIdx.x * 16;
      uv4 q0, q1, q2;
      q0.x = ntag; q0.y = __float_as_uint(hA.x);
      q0.z = __float_as_uint(hA.y); q0.w = __float_as_uint(hA.z);
      q1.x = ntag; q1.y = __float_as_uint(hA.w);
      q1.z = __float_as_uint(hB.x); q1.w = __float_as_uint(hB.y);
      q2.x = ntag; q2.y = __float_as_uint(hB.z);
      q2.z = __float_as_uint(hB.w); q2.w = 0u;
      bypass_store_x4(line, q0);
      bypass_store_x4(line + 4, q1);
      bypass_store_x4(line + 8, q2);
    }
    // history store off the critical path (ack drains during next poll)
    if (i == 0) {
      hall[(size_t)t * H_DIM + jg] = f2b(hn);
    }
  }
}

// ---------------------------------------------------------------------------
// 3a) Y[T,1024](bf16) = X[T,1024](bf16) @ W[1024,1024](f32) + bias(f32)
//     64x64 tile, 256 thr, 4x4 micro-tile, K-step 16, f32 accumulate.
// ---------------------------------------------------------------------------
__global__ __launch_bounds__(256) void ddsp_gemm_bias(
    const u16* __restrict__ X, const float* __restrict__ Wt,
    const float* __restrict__ bias, u16* __restrict__ Y)
{
  __shared__ float As[16][64];  // transposed A tile: As[kk][m]
  __shared__ float Bs[16][64];
  const int tid = threadIdx.x;
  const int R0 = blockIdx.x * 64;
  const int N0 = blockIdx.y * 64;
  const int tx = tid & 15, ty = tid >> 4;
  const int am = tid >> 2, ak = (tid & 3) * 4;   // A staging
  const int bk = tid >> 4, bn = (tid & 15) * 4;  // B staging
  float acc[4][4] = {};

  for (int k0 = 0; k0 < H_DIM; k0 += 16) {
    const ushort4 a4 = *(const ushort4*)(X + (size_t)(R0 + am) * H_DIM + k0 + ak);
    const float4 b4 = *(const float4*)(Wt + (size_t)(k0 + bk) * H_DIM + N0 + bn);
    As[ak + 0][am] = b2f(a4.x); As[ak + 1][am] = b2f(a4.y);
    As[ak + 2][am] = b2f(a4.z); As[ak + 3][am] = b2f(a4.w);
    *(float4*)&Bs[bk][bn] = b4;
    __syncthreads();
#pragma unroll
    for (int kk = 0; kk < 16; ++kk) {
      const float4 av = *(const float4*)&As[kk][ty * 4];
      const float4 bv = *(const float4*)&Bs[kk][tx * 4];
      const float a[4] = {av.x, av.y, av.z, av.w};
      const float b[4] = {bv.x, bv.y, bv.z, bv.w};
#pragma unroll
      for (int mi = 0; mi < 4; ++mi)
#pragma unroll
        for (int ni = 0; ni < 4; ++ni)
          acc[mi][ni] = fmaf(a[mi], b[ni], acc[mi][ni]);
    }
    __syncthreads();
  }
  const float4 bv4 = *(const float4*)(bias + N0 + tx * 4);
#pragma unroll
  for (int mi = 0; mi < 4; ++mi) {
    ushort4 st;
    st.x = f2b(acc[mi][0] + bv4.x);
    st.y = f2b(acc[mi][1] + bv4.y);
    st.z = f2b(acc[mi][2] + bv4.z);
    st.w = f2b(acc[mi][3] + bv4.w);
    *(ushort4*)(Y + (size_t)(R0 + ty * 4 + mi) * H_DIM + N0 + tx * 4) = st;
  }
}

// ---------------------------------------------------------------------------
// 3b) in-place LayerNorm + ReLU over bf16 rows of Y (block = row).
// ---------------------------------------------------------------------------
__global__ __launch_bounds__(256) void ddsp_ln_relu(
    u16* __restrict__ Y, const float* __restrict__ scale, const float* __restrict__ bias)
{
  __shared__ float wsum[4], wsq[4];
  const int row = blockIdx.x, tid = threadIdx.x;
  const ushort4 r4 = *(const ushort4*)(Y + (size_t)row * H_DIM + tid * 4);
  float x[4] = {b2f(r4.x), b2f(r4.y), b2f(r4.z), b2f(r4.w)};
  float s = x[0] + x[1] + x[2] + x[3];
  float q = x[0] * x[0] + x[1] * x[1] + x[2] * x[2] + x[3] * x[3];
#pragma unroll
  for (int off = 32; off >= 1; off >>= 1) {
    s += __shfl_down(s, off);
    q += __shfl_down(q, off);
  }
  if ((tid & 63) == 0) { wsum[tid >> 6] = s; wsq[tid >> 6] = q; }
  __syncthreads();
  const float ts = wsum[0] + wsum[1] + wsum[2] + wsum[3];
  const float tq = wsq[0] + wsq[1] + wsq[2] + wsq[3];
  const float mu = ts * (1.0f / H_DIM);
  const float var = tq * (1.0f / H_DIM) - mu * mu;
  const float rstd = rsqrtf(fmaxf(var, 0.f) + 1e-6f);
  const float4 sc = *(const float4*)(scale + tid * 4);
  const float4 bi = *(const float4*)(bias + tid * 4);
  ushort4 st;
  st.x = f2b(fmaxf((x[0] - mu) * rstd * sc.x + bi.x, 0.f));
  st.y = f2b(fmaxf((x[1] - mu) * rstd * sc.y + bi.y, 0.f));
  st.z = f2b(fmaxf((x[2] - mu) * rstd * sc.z + bi.z, 0.f));
  st.w = f2b(fmaxf((x[3] - mu) * rstd * sc.w + bi.w, 0.f));
  *(ushort4*)(Y + (size_t)row * H_DIM + tid * 4) = st;
}

// ---------------------------------------------------------------------------
// 4) heads: block = timestep. threads 0..99 harm, 100..164 noise, 165 amp.
//    Hf is bf16; weights/bias/output f32.
// ---------------------------------------------------------------------------
__global__ __launch_bounds__(256) void ddsp_heads(
    const u16* __restrict__ Hf,
    const float* __restrict__ aW, const float* __restrict__ ab,
    const float* __restrict__ hW, const float* __restrict__ hb,
    const float* __restrict__ nW, const float* __restrict__ nb,
    float* __restrict__ out)
{
  __shared__ float lh[H_DIM];
  __shared__ float se[128];
  __shared__ float sred[2];  // [0]=amp, [1]=harm sum
  const int t = blockIdx.x, tid = threadIdx.x;
  const ushort4 h4 = *(const ushort4*)(Hf + (size_t)t * H_DIM + tid * 4);
  lh[tid * 4 + 0] = b2f(h4.x); lh[tid * 4 + 1] = b2f(h4.y);
  lh[tid * 4 + 2] = b2f(h4.z); lh[tid * 4 + 3] = b2f(h4.w);
  __syncthreads();

  if (tid < NHARM) {
    float acc = 0.f;
    for (int k = 0; k < H_DIM; k += 4) {
      const float4 hv = *(const float4*)(lh + k);
      acc = fmaf(hv.x, hW[(k + 0) * NHARM + tid], acc);
      acc = fmaf(hv.y, hW[(k + 1) * NHARM + tid], acc);
      acc = fmaf(hv.z, hW[(k + 2) * NHARM + tid], acc);
      acc = fmaf(hv.w, hW[(k + 3) * NHARM + tid], acc);
    }
    se[tid] = exp_sig(acc + hb[tid]);
  } else if (tid < NHARM + NNOISE) {
    const int n = tid - NHARM;
    float acc = 0.f;
    for (int k = 0; k < H_DIM; k += 4) {
      const float4 hv = *(const float4*)(lh + k);
      acc = fmaf(hv.x, nW[(k + 0) * NNOISE + n], acc);
      acc = fmaf(hv.y, nW[(k + 1) * NNOISE + n], acc);
      acc = fmaf(hv.z, nW[(k + 2) * NNOISE + n], acc);
      acc = fmaf(hv.w, nW[(k + 3) * NNOISE + n], acc);
    }
    out[(size_t)T_STEPS * NHARM + (size_t)t * NNOISE + n] = acc + nb[n];
  } else if (tid == NHARM + NNOISE) {
    float acc = 0.f;
    for (int k = 0; k < H_DIM; k += 4) {
      const float4 hv = *(const float4*)(lh + k);
      acc = fmaf(hv.x, aW[k + 0], acc);
      acc = fmaf(hv.y, aW[k + 1], acc);
      acc = fmaf(hv.z, aW[k + 2], acc);
      acc = fmaf(hv.w, aW[k + 3], acc);
    }
    sred[0] = exp_sig(acc + ab[0]);
  }
  if (tid >= NHARM && tid < 128) se[tid] = 0.f;  // pad for reduce
  __syncthreads();
  if (tid < 64) {
    float s2 = se[tid] + se[tid + 64];
#pragma unroll
    for (int off = 32; off >= 1; off >>= 1) s2 += __shfl_down(s2, off);
    if (tid == 0) sred[1] = s2;
  }
  __syncthreads();
  if (tid < NHARM) {
    out[(size_t)t * NHARM + tid] = sred[0] * se[tid] / (sred[1] + 1e-8f);
  }
}

// ---------------------------------------------------------------------------
extern "C" void kernel_launch(void* const* d_in, const int* in_sizes, int n_in,
                              void* d_out, int out_size, void* d_ws, size_t ws_size,
                              hipStream_t stream)
{
  (void)in_sizes; (void)n_in; (void)out_size;
  const float* f0   = (const float*)d_in[0];
  const float* loud = (const float*)d_in[1];
  const float* Win  = (const float*)d_in[2];
  const float* bin  = (const float*)d_in[3];
  const float* Wi   = (const float*)d_in[4];
  const float* Wh   = (const float*)d_in[5];
  const float* bh   = (const float*)d_in[6];
  const float* h0   = (const float*)d_in[7];
  const float* mlpW = (const float*)d_in[8];
  const float* mlpb = (const float*)d_in[9];
  const float* lnS  = (const float*)d_in[10];
  const float* lnB  = (const float*)d_in[11];
  const float* aW   = (const float*)d_in[12];
  const float* ab   = (const float*)d_in[13];
  const float* hW   = (const float*)d_in[14];
  const float* hb   = (const float*)d_in[15];
  const float* nW   = (const float*)d_in[16];
  const float* nb   = (const float*)d_in[17];
  float* out = (float*)d_out;

  char* ws = (char*)d_ws;
  float*    U     = (float*)(ws);                    // 3072 f32
  float*    V     = (float*)(ws + 12288);            // 3072 f32
  float*    Wc    = (float*)(ws + 24576);            // 3072 f32
  unsigned* slots = (unsigned*)(ws + 36864);         // 2 x 128 x 64B = 16 KB
  u16* bufA = (u16*)(ws + 53248);                               // [T,H] bf16
  u16* bufB = (u16*)(ws + 53248 + (size_t)T_STEPS * H_DIM * 2); // [T,H] bf16

  const size_t needed = 53248 + 2 * (size_t)T_STEPS * H_DIM * 2;  // ~134.3 MB
  if (ws_size < needed) {
    // Workspace too small: do nothing -> bench reports absmax == max|ref|.
    return;
  }

  ddsp_precompute<<<16, 256, 0, stream>>>(Win, bin, Wi, h0, U, V, Wc, slots);
  ddsp_gru<<<GRU_NB, 256, 0, stream>>>(f0, loud, Wh, bh, U, V, Wc, slots, bufA);

  dim3 gg(T_STEPS / 64, H_DIM / 64);
  ddsp_gemm_bias<<<gg, 256, 0, stream>>>(bufA, mlpW, mlpb, bufB);
  ddsp_ln_relu<<<T_STEPS, 256, 0, stream>>>(bufB, lnS, lnB);
  ddsp_gemm_bias<<<gg, 256, 0, stream>>>(bufB, mlpW + (size_t)H_DIM * H_DIM, mlpb + H_DIM, bufA);
  ddsp_ln_relu<<<T_STEPS, 256, 0, stream>>>(bufA, lnS + H_DIM, lnB + H_DIM);
  ddsp_gemm_bias<<<gg, 256, 0, stream>>>(bufA, mlpW + 2 * (size_t)H_DIM * H_DIM, mlpb + 2 * H_DIM, bufB);
  ddsp_ln_relu<<<T_STEPS, 256, 0, stream>>>(bufB, lnS + 2 * H_DIM, lnB + 2 * H_DIM);

  ddsp_heads<<<T_STEPS, 256, 0, stream>>>(bufB, aW, ab, hW, hb, nW, nb, out);
}

// Round 10
// 115572.742 us; speedup vs baseline: 2.3748x; 1.0004x over previous
//
#include <hip/hip_runtime.h>
#include <cstdint>
#include <cmath>

// ---------------------------------------------------------------------------
// DDSP decoder on MI355X — inputs/outputs float32 (per reference dtypes).
//   1) precompute: gi_t = f0_t*U + loud_t*V + W  (input GEMM is rank-2+const)
//   2) persistent GRU: 128 blocks x 256 thr; Wh slice (8 cols x 3 gates, f32)
//      in LDS (96 KB). Fused h-exchange+barrier: each block publishes its 8 h
//      values into its own 64B slot with a tag in each 16B quad (tag==step
//      validates the quad; no tearing, no fences). Parity double-buffered
//      slot sets (overwrite-safety by induction). ONE coherence round trip
//      per step. r10: AGENT scope (sc1) instead of r9's system scope
//      (sc0 sc1) — system scope forced every publish/poll to HBM (r9:
//      FETCH 3.1GB, WRITE exactly 16KB/step write-through, ~900cy/hop);
//      agent scope stops at the device-common Infinity Cache (same
//      correctness as r7's compiler-generated agent atomics).
//      History: r5 fences = L2 writeback storm; r6 all-poll-all = LLC line
//      contention; r7 master-broadcast 3 round trips; r8/r9 fused protocol.
//   3) 3x (64x64-tile GEMM bf16-in/f32-acc/bf16-out + bias) + LN+ReLU.
//   4) heads: per-t block; amp/harm/noise projections, exp_sigmoid, normalize.
// ---------------------------------------------------------------------------

#define T_STEPS 32768
#define H_DIM   1024
#define H3      3072
#define NHARM   100
#define NNOISE  65
#define GRU_NB  128
#define GRU_CPB 8      // columns (h outputs) per block

typedef unsigned short u16;
typedef unsigned uv4 __attribute__((ext_vector_type(4)));

__device__ __forceinline__ float b2f(u16 u) {
  union { unsigned u; float f; } x; x.u = ((unsigned)u) << 16; return x.f;
}
__device__ __forceinline__ u16 f2b(float f) {
  unsigned v = __float_as_uint(f);
  unsigned r = (v + 0x7FFFu + ((v >> 16) & 1u)) >> 16;  // RNE
  return (u16)r;
}
__device__ __forceinline__ float sigm(float x) { return 1.0f / (1.0f + expf(-x)); }
__device__ __forceinline__ float exp_sig(float x) {
  // 2.0 * sigmoid(x)^ln(10) + 1e-7
  float s = sigm(x);
  return 2.0f * expf(2.302585093f * logf(s)) + 1e-7f;
}

// 48B agent-scope (sc1: L2-bypass, coherent at the Infinity Cache) line read,
// 3 dwordx4 back-to-back, one drain: one IC access latency for tag AND data.
__device__ __forceinline__ void bypass_load_3x4(const unsigned* p,
                                                uv4& a, uv4& b, uv4& c) {
  asm volatile("global_load_dwordx4 %0, %3, off sc1\n\t"
               "global_load_dwordx4 %1, %3, off offset:16 sc1\n\t"
               "global_load_dwordx4 %2, %3, off offset:32 sc1\n\t"
               "s_waitcnt vmcnt(0)"
               : "=v"(a), "=v"(b), "=v"(c) : "v"(p) : "memory");
}
__device__ __forceinline__ void bypass_store_x4(unsigned* p, uv4 v) {
  asm volatile("global_store_dwordx4 %0, %1, off sc1"
               :: "v"(p), "v"(v) : "memory");
}

// slots layout: 2 sets (step parity) x 128 lines x 16 u32 (64B).
// line = [tag,h0,h1,h2][tag,h3,h4,h5][tag,h6,h7,-][----]

// ---------------------------------------------------------------------------
// 1) U[j] = sum_h Win[0,h]*Wi[h,j]; V[j] = sum_h Win[1,h]*Wi[h,j];
//    W[j] = sum_h bin[h]*Wi[h,j].  Blocks 12..15: init h slot lines.
//    (plain stores: end-of-kernel release makes them device-visible)
// ---------------------------------------------------------------------------
__global__ __launch_bounds__(256) void ddsp_precompute(
    const float* __restrict__ Win, const float* __restrict__ bin,
    const float* __restrict__ Wi, const float* __restrict__ h0,
    float* __restrict__ U, float* __restrict__ V, float* __restrict__ Wc,
    unsigned* __restrict__ slots)
{
  const int gid = blockIdx.x * 256 + threadIdx.x;
  if (blockIdx.x < 12) {
    const int j = gid;  // 0..3071
    float su = 0.f, sv = 0.f, sw = 0.f;
    for (int h = 0; h < H_DIM; ++h) {
      const float wv = Wi[h * H3 + j];        // lanes j consecutive -> coalesced
      su = fmaf(Win[h], wv, su);
      sv = fmaf(Win[H_DIM + h], wv, sv);
      sw = fmaf(bin[h], wv, sw);
    }
    U[j] = su; V[j] = sv; Wc[j] = sw;
  } else {
    const int idx = gid - 12 * 256;           // 0..1023
    if (idx < GRU_NB) {
      unsigned* l0 = slots + idx * 16;            // parity-0 set: tag 0 + h0
      unsigned* l1 = slots + GRU_NB * 16 + idx * 16;  // parity-1 set
      l0[0] = 0u; l0[1] = __float_as_uint(h0[idx * 8 + 0]);
      l0[2] = __float_as_uint(h0[idx * 8 + 1]);
      l0[3] = __float_as_uint(h0[idx * 8 + 2]);
      l0[4] = 0u; l0[5] = __float_as_uint(h0[idx * 8 + 3]);
      l0[6] = __float_as_uint(h0[idx * 8 + 4]);
      l0[7] = __float_as_uint(h0[idx * 8 + 5]);
      l0[8] = 0u; l0[9] = __float_as_uint(h0[idx * 8 + 6]);
      l0[10] = __float_as_uint(h0[idx * 8 + 7]);
      l0[11] = 0u;
      l1[0] = 0u; l1[4] = 0u; l1[8] = 0u;     // != any odd tag (ws poisoned)
    }
  }
}

// ---------------------------------------------------------------------------
// 2) persistent GRU.  128 blocks x 256 thr.  thread = (jl = tid>>5 col 0..7,
//    i = tid&31 k-chunk).  Wh slice [3][8][1024] f32 staged in LDS once.
//    Per step: tid<128 poll+assemble h from slot lines (1 line each) -> LDS,
//    24 ds_read_b128 + 96 FMA per thread, 32-lane butterfly reduce, gates on
//    i==0 -> LDS gather, tid0 publishes the block's tagged line. hall history
//    store issued after publish so its ack drains during the next poll.
// ---------------------------------------------------------------------------
__global__ __launch_bounds__(256, 1) void ddsp_gru(
    const float* __restrict__ f0, const float* __restrict__ loud,
    const float* __restrict__ Wh, const float* __restrict__ bh,
    const float* __restrict__ U, const float* __restrict__ V,
    const float* __restrict__ Wc,
    unsigned* __restrict__ slots, u16* __restrict__ hall)
{
  __shared__ float wlds[3 * GRU_CPB * H_DIM];  // 96 KB: [g][c][k]
  __shared__ float lds_h[H_DIM];               // 4 KB
  __shared__ float lds_hout[GRU_CPB];
  const int tid = threadIdx.x;
  const int i  = tid & 31;
  const int jl = tid >> 5;
  const int jg = blockIdx.x * GRU_CPB + jl;

  // One-time LDS weight stage: wlds[g][c][k] = Wh[k][g*1024 + block*8 + c].
  for (int g = 0; g < 3; ++g) {
    for (int c = 0; c < GRU_CPB; ++c) {
      const int col = g * H_DIM + blockIdx.x * GRU_CPB + c;
#pragma unroll
      for (int e = 0; e < 4; ++e) {
        const int k = tid * 4 + e;
        wlds[(g * GRU_CPB + c) * H_DIM + k] = Wh[(size_t)k * H3 + col];
      }
    }
  }

  float ur = 0.f, uz = 0.f, un = 0.f, vr = 0.f, vz = 0.f, vn = 0.f;
  float wr = 0.f, wz = 0.f, wn = 0.f, bhr = 0.f, bhz = 0.f, bhn = 0.f;
  if (i == 0) {
    ur = U[jg]; uz = U[jg + 1024]; un = U[jg + 2048];
    vr = V[jg]; vz = V[jg + 1024]; vn = V[jg + 2048];
    wr = Wc[jg]; wz = Wc[jg + 1024]; wn = Wc[jg + 2048];
    bhr = bh[jg]; bhz = bh[jg + 1024]; bhn = bh[jg + 2048];
  }
  __syncthreads();

  const float* wl0 = wlds + (0 * GRU_CPB + jl) * H_DIM;
  const float* wl1 = wlds + (1 * GRU_CPB + jl) * H_DIM;
  const float* wl2 = wlds + (2 * GRU_CPB + jl) * H_DIM;

  for (int t = 0; t < T_STEPS; ++t) {
    const unsigned tag = (unsigned)t;
    unsigned* slot_rd = slots + (size_t)(t & 1) * GRU_NB * 16;
    unsigned* slot_wr = slots + (size_t)((t + 1) & 1) * GRU_NB * 16;

    // prefetch scalar inputs off the critical path
    const float fv = f0[t];
    const float lv = loud[t];

    // poll+assemble: thread tid owns line tid. tag==t in all 3 quads
    // validates the quads' data (written with the same store).
    if (tid < GRU_NB) {
      const unsigned* line = slot_rd + tid * 16;
      uv4 a, b, c;
      do {
        bypass_load_3x4(line, a, b, c);
      } while (a.x != tag || b.x != tag || c.x != tag);
      float4 hA, hB;
      hA.x = __uint_as_float(a.y); hA.y = __uint_as_float(a.z);
      hA.z = __uint_as_float(a.w); hA.w = __uint_as_float(b.y);
      hB.x = __uint_as_float(b.z); hB.y = __uint_as_float(b.w);
      hB.z = __uint_as_float(c.y); hB.w = __uint_as_float(c.z);
      *(float4*)(lds_h + tid * 8) = hA;
      *(float4*)(lds_h + tid * 8 + 4) = hB;
    }
    __syncthreads();

    float a0 = 0.f, a1 = 0.f, a2 = 0.f;
    const int kbase = i << 5;  // i*32
#pragma unroll
    for (int it = 0; it < 8; ++it) {
      const int kk = kbase + (((it + i) & 7) << 2);  // rotation spreads banks
      const float4 h4 = *(const float4*)(lds_h + kk);
      const float4 wa = *(const float4*)(wl0 + kk);
      const float4 wb = *(const float4*)(wl1 + kk);
      const float4 wc4 = *(const float4*)(wl2 + kk);
      a0 = fmaf(wa.x, h4.x, a0); a0 = fmaf(wa.y, h4.y, a0);
      a0 = fmaf(wa.z, h4.z, a0); a0 = fmaf(wa.w, h4.w, a0);
      a1 = fmaf(wb.x, h4.x, a1); a1 = fmaf(wb.y, h4.y, a1);
      a1 = fmaf(wb.z, h4.z, a1); a1 = fmaf(wb.w, h4.w, a1);
      a2 = fmaf(wc4.x, h4.x, a2); a2 = fmaf(wc4.y, h4.y, a2);
      a2 = fmaf(wc4.z, h4.z, a2); a2 = fmaf(wc4.w, h4.w, a2);
    }
    // butterfly reduce over the 32-lane group
#pragma unroll
    for (int m = 1; m < 32; m <<= 1) {
      a0 += __shfl_xor(a0, m);
      a1 += __shfl_xor(a1, m);
      a2 += __shfl_xor(a2, m);
    }
    float hn = 0.f;
    if (i == 0) {
      const float gir = fmaf(fv, ur, fmaf(lv, vr, wr));
      const float giz = fmaf(fv, uz, fmaf(lv, vz, wz));
      const float gin = fmaf(fv, un, fmaf(lv, vn, wn));
      const float r = sigm(gir + a0 + bhr);
      const float z = sigm(giz + a1 + bhz);
      const float n = tanhf(fmaf(r, a2 + bhn, gin));  // b_h[n] inside r*( )
      const float hp = lds_h[jg];
      hn = (1.0f - z) * n + z * hp;
      lds_hout[jl] = hn;
    }
    __syncthreads();

    // publish: tag t+1 embedded in every quad; parity double-buffer makes
    // the overwrite race-free (see header). No drain needed (self-validating).
    if (tid == 0) {
      const unsigned ntag = (unsigned)(t + 1);
      const float4 hA = *(const float4*)(lds_hout);
      const float4 hB = *(const float4*)(lds_hout + 4);
      unsigned* line = slot_wr + blockIdx.x * 16;
      uv4 q0, q1, q2;
      q0.x = ntag; q0.y = __float_as_uint(hA.x);
      q0.z = __float_as_uint(hA.y); q0.w = __float_as_uint(hA.z);
      q1.x = ntag; q1.y = __float_as_uint(hA.w);
      q1.z = __float_as_uint(hB.x); q1.w = __float_as_uint(hB.y);
      q2.x = ntag; q2.y = __float_as_uint(hB.z);
      q2.z = __float_as_uint(hB.w); q2.w = 0u;
      bypass_store_x4(line, q0);
      bypass_store_x4(line + 4, q1);
      bypass_store_x4(line + 8, q2);
    }
    // history store off the critical path (ack drains during next poll)
    if (i == 0) {
      hall[(size_t)t * H_DIM + jg] = f2b(hn);
    }
  }
}

// ---------------------------------------------------------------------------
// 3a) Y[T,1024](bf16) = X[T,1024](bf16) @ W[1024,1024](f32) + bias(f32)
//     64x64 tile, 256 thr, 4x4 micro-tile, K-step 16, f32 accumulate.
// ---------------------------------------------------------------------------
__global__ __launch_bounds__(256) void ddsp_gemm_bias(
    const u16* __restrict__ X, const float* __restrict__ Wt,
    const float* __restrict__ bias, u16* __restrict__ Y)
{
  __shared__ float As[16][64];  // transposed A tile: As[kk][m]
  __shared__ float Bs[16][64];
  const int tid = threadIdx.x;
  const int R0 = blockIdx.x * 64;
  const int N0 = blockIdx.y * 64;
  const int tx = tid & 15, ty = tid >> 4;
  const int am = tid >> 2, ak = (tid & 3) * 4;   // A staging
  const int bk = tid >> 4, bn = (tid & 15) * 4;  // B staging
  float acc[4][4] = {};

  for (int k0 = 0; k0 < H_DIM; k0 += 16) {
    const ushort4 a4 = *(const ushort4*)(X + (size_t)(R0 + am) * H_DIM + k0 + ak);
    const float4 b4 = *(const float4*)(Wt + (size_t)(k0 + bk) * H_DIM + N0 + bn);
    As[ak + 0][am] = b2f(a4.x); As[ak + 1][am] = b2f(a4.y);
    As[ak + 2][am] = b2f(a4.z); As[ak + 3][am] = b2f(a4.w);
    *(float4*)&Bs[bk][bn] = b4;
    __syncthreads();
#pragma unroll
    for (int kk = 0; kk < 16; ++kk) {
      const float4 av = *(const float4*)&As[kk][ty * 4];
      const float4 bv = *(const float4*)&Bs[kk][tx * 4];
      const float a[4] = {av.x, av.y, av.z, av.w};
      const float b[4] = {bv.x, bv.y, bv.z, bv.w};
#pragma unroll
      for (int mi = 0; mi < 4; ++mi)
#pragma unroll
        for (int ni = 0; ni < 4; ++ni)
          acc[mi][ni] = fmaf(a[mi], b[ni], acc[mi][ni]);
    }
    __syncthreads();
  }
  const float4 bv4 = *(const float4*)(bias + N0 + tx * 4);
#pragma unroll
  for (int mi = 0; mi < 4; ++mi) {
    ushort4 st;
    st.x = f2b(acc[mi][0] + bv4.x);
    st.y = f2b(acc[mi][1] + bv4.y);
    st.z = f2b(acc[mi][2] + bv4.z);
    st.w = f2b(acc[mi][3] + bv4.w);
    *(ushort4*)(Y + (size_t)(R0 + ty * 4 + mi) * H_DIM + N0 + tx * 4) = st;
  }
}

// ---------------------------------------------------------------------------
// 3b) in-place LayerNorm + ReLU over bf16 rows of Y (block = row).
// ---------------------------------------------------------------------------
__global__ __launch_bounds__(256) void ddsp_ln_relu(
    u16* __restrict__ Y, const float* __restrict__ scale, const float* __restrict__ bias)
{
  __shared__ float wsum[4], wsq[4];
  const int row = blockIdx.x, tid = threadIdx.x;
  const ushort4 r4 = *(const ushort4*)(Y + (size_t)row * H_DIM + tid * 4);
  float x[4] = {b2f(r4.x), b2f(r4.y), b2f(r4.z), b2f(r4.w)};
  float s = x[0] + x[1] + x[2] + x[3];
  float q = x[0] * x[0] + x[1] * x[1] + x[2] * x[2] + x[3] * x[3];
#pragma unroll
  for (int off = 32; off >= 1; off >>= 1) {
    s += __shfl_down(s, off);
    q += __shfl_down(q, off);
  }
  if ((tid & 63) == 0) { wsum[tid >> 6] = s; wsq[tid >> 6] = q; }
  __syncthreads();
  const float ts = wsum[0] + wsum[1] + wsum[2] + wsum[3];
  const float tq = wsq[0] + wsq[1] + wsq[2] + wsq[3];
  const float mu = ts * (1.0f / H_DIM);
  const float var = tq * (1.0f / H_DIM) - mu * mu;
  const float rstd = rsqrtf(fmaxf(var, 0.f) + 1e-6f);
  const float4 sc = *(const float4*)(scale + tid * 4);
  const float4 bi = *(const float4*)(bias + tid * 4);
  ushort4 st;
  st.x = f2b(fmaxf((x[0] - mu) * rstd * sc.x + bi.x, 0.f));
  st.y = f2b(fmaxf((x[1] - mu) * rstd * sc.y + bi.y, 0.f));
  st.z = f2b(fmaxf((x[2] - mu) * rstd * sc.z + bi.z, 0.f));
  st.w = f2b(fmaxf((x[3] - mu) * rstd * sc.w + bi.w, 0.f));
  *(ushort4*)(Y + (size_t)row * H_DIM + tid * 4) = st;
}

// ---------------------------------------------------------------------------
// 4) heads: block = timestep. threads 0..99 harm, 100..164 noise, 165 amp.
//    Hf is bf16; weights/bias/output f32.
// ---------------------------------------------------------------------------
__global__ __launch_bounds__(256) void ddsp_heads(
    const u16* __restrict__ Hf,
    const float* __restrict__ aW, const float* __restrict__ ab,
    const float* __restrict__ hW, const float* __restrict__ hb,
    const float* __restrict__ nW, const float* __restrict__ nb,
    float* __restrict__ out)
{
  __shared__ float lh[H_DIM];
  __shared__ float se[128];
  __shared__ float sred[2];  // [0]=amp, [1]=harm sum
  const int t = blockIdx.x, tid = threadIdx.x;
  const ushort4 h4 = *(const ushort4*)(Hf + (size_t)t * H_DIM + tid * 4);
  lh[tid * 4 + 0] = b2f(h4.x); lh[tid * 4 + 1] = b2f(h4.y);
  lh[tid * 4 + 2] = b2f(h4.z); lh[tid * 4 + 3] = b2f(h4.w);
  __syncthreads();

  if (tid < NHARM) {
    float acc = 0.f;
    for (int k = 0; k < H_DIM; k += 4) {
      const float4 hv = *(const float4*)(lh + k);
      acc = fmaf(hv.x, hW[(k + 0) * NHARM + tid], acc);
      acc = fmaf(hv.y, hW[(k + 1) * NHARM + tid], acc);
      acc = fmaf(hv.z, hW[(k + 2) * NHARM + tid], acc);
      acc = fmaf(hv.w, hW[(k + 3) * NHARM + tid], acc);
    }
    se[tid] = exp_sig(acc + hb[tid]);
  } else if (tid < NHARM + NNOISE) {
    const int n = tid - NHARM;
    float acc = 0.f;
    for (int k = 0; k < H_DIM; k += 4) {
      const float4 hv = *(const float4*)(lh + k);
      acc = fmaf(hv.x, nW[(k + 0) * NNOISE + n], acc);
      acc = fmaf(hv.y, nW[(k + 1) * NNOISE + n], acc);
      acc = fmaf(hv.z, nW[(k + 2) * NNOISE + n], acc);
      acc = fmaf(hv.w, nW[(k + 3) * NNOISE + n], acc);
    }
    out[(size_t)T_STEPS * NHARM + (size_t)t * NNOISE + n] = acc + nb[n];
  } else if (tid == NHARM + NNOISE) {
    float acc = 0.f;
    for (int k = 0; k < H_DIM; k += 4) {
      const float4 hv = *(const float4*)(lh + k);
      acc = fmaf(hv.x, aW[k + 0], acc);
      acc = fmaf(hv.y, aW[k + 1], acc);
      acc = fmaf(hv.z, aW[k + 2], acc);
      acc = fmaf(hv.w, aW[k + 3], acc);
    }
    sred[0] = exp_sig(acc + ab[0]);
  }
  if (tid >= NHARM && tid < 128) se[tid] = 0.f;  // pad for reduce
  __syncthreads();
  if (tid < 64) {
    float s2 = se[tid] + se[tid + 64];
#pragma unroll
    for (int off = 32; off >= 1; off >>= 1) s2 += __shfl_down(s2, off);
    if (tid == 0) sred[1] = s2;
  }
  __syncthreads();
  if (tid < NHARM) {
    out[(size_t)t * NHARM + tid] = sred[0] * se[tid] / (sred[1] + 1e-8f);
  }
}

// ---------------------------------------------------------------------------
extern "C" void kernel_launch(void* const* d_in, const int* in_sizes, int n_in,
                              void* d_out, int out_size, void* d_ws, size_t ws_size,
                              hipStream_t stream)
{
  (void)in_sizes; (void)n_in; (void)out_size;
  const float* f0   = (const float*)d_in[0];
  const float* loud = (const float*)d_in[1];
  const float* Win  = (const float*)d_in[2];
  const float* bin  = (const float*)d_in[3];
  const float* Wi   = (const float*)d_in[4];
  const float* Wh   = (const float*)d_in[5];
  const float* bh   = (const float*)d_in[6];
  const float* h0   = (const float*)d_in[7];
  const float* mlpW = (const float*)d_in[8];
  const float* mlpb = (const float*)d_in[9];
  const float* lnS  = (const float*)d_in[10];
  const float* lnB  = (const float*)d_in[11];
  const float* aW   = (const float*)d_in[12];
  const float* ab   = (const float*)d_in[13];
  const float* hW   = (const float*)d_in[14];
  const float* hb   = (const float*)d_in[15];
  const float* nW   = (const float*)d_in[16];
  const float* nb   = (const float*)d_in[17];
  float* out = (float*)d_out;

  char* ws = (char*)d_ws;
  float*    U     = (float*)(ws);                    // 3072 f32
  float*    V     = (float*)(ws + 12288);            // 3072 f32
  float*    Wc    = (float*)(ws + 24576);            // 3072 f32
  unsigned* slots = (unsigned*)(ws + 36864);         // 2 x 128 x 64B = 16 KB
  u16* bufA = (u16*)(ws + 53248);                               // [T,H] bf16
  u16* bufB = (u16*)(ws + 53248 + (size_t)T_STEPS * H_DIM * 2); // [T,H] bf16

  const size_t needed = 53248 + 2 * (size_t)T_STEPS * H_DIM * 2;  // ~134.3 MB
  if (ws_size < needed) {
    // Workspace too small: do nothing -> bench reports absmax == max|ref|.
    return;
  }

  ddsp_precompute<<<16, 256, 0, stream>>>(Win, bin, Wi, h0, U, V, Wc, slots);
  ddsp_gru<<<GRU_NB, 256, 0, stream>>>(f0, loud, Wh, bh, U, V, Wc, slots, bufA);

  dim3 gg(T_STEPS / 64, H_DIM / 64);
  ddsp_gemm_bias<<<gg, 256, 0, stream>>>(bufA, mlpW, mlpb, bufB);
  ddsp_ln_relu<<<T_STEPS, 256, 0, stream>>>(bufB, lnS, lnB);
  ddsp_gemm_bias<<<gg, 256, 0, stream>>>(bufB, mlpW + (size_t)H_DIM * H_DIM, mlpb + H_DIM, bufA);
  ddsp_ln_relu<<<T_STEPS, 256, 0, stream>>>(bufA, lnS + H_DIM, lnB + H_DIM);
  ddsp_gemm_bias<<<gg, 256, 0, stream>>>(bufA, mlpW + 2 * (size_t)H_DIM * H_DIM, mlpb + 2 * H_DIM, bufB);
  ddsp_ln_relu<<<T_STEPS, 256, 0, stream>>>(bufB, lnS + 2 * H_DIM, lnB + 2 * H_DIM);

  ddsp_heads<<<T_STEPS, 256, 0, stream>>>(bufB, aW, ab, hW, hb, nW, nb, out);
}